// Round 21
// baseline (1021.871 us; speedup 1.0000x reference)
//
#include <hip/hip_runtime.h>
#include <hip/hip_bf16.h>

#define T_ 12
#define N_ 10000
#define C_ 32
#define E_ 320000
#define SUP_ 3
#define TN_ (T_*N_)
#define CHUNKB 24576

typedef __attribute__((ext_vector_type(4))) float f32x4;
typedef __attribute__((ext_vector_type(8))) short bf16x8;
typedef __attribute__((ext_vector_type(4))) short bf16x4;

__device__ __forceinline__ short bf16c(float f) {
  __hip_bfloat16 b = __float2bfloat16(f);
  return (short)__builtin_bit_cast(unsigned short, b);
}

#if __has_builtin(__builtin_amdgcn_exp2f)
#define EXP2F(x) __builtin_amdgcn_exp2f(x)
#else
#define EXP2F(x) exp2f(x)
#endif

// async global->LDS, 16B per lane; lds base wave-uniform (HW adds lane*16)
__device__ __forceinline__ void gload_lds16(const void* g, void* l) {
  __builtin_amdgcn_global_load_lds(
      (__attribute__((address_space(1))) void*)(void*)g,
      (__attribute__((address_space(3))) void*)l,
      16, 0, 0);
}

// prm layout (float offsets)
#define PRM_ATTN 0
#define PRM_G    64
#define PRM_H    1088
#define PRM_G1   2112
#define PRM_G2   2144
#define PRM_HB   2176
#define PRM_G0   2208

// ---------------- small precompute: attn vector + folded attention mats ----------------
__global__ __launch_bounds__(256) void k_prep(
    const float* __restrict__ timeoh, const float* __restrict__ temb_w,
    const float* __restrict__ atten_pool,
    const float* __restrict__ q_w, const float* __restrict__ q_b,
    const float* __restrict__ k_w, const float* __restrict__ k_b,
    const float* __restrict__ v_w, const float* __restrict__ v_b,
    const float* __restrict__ dense_w, const float* __restrict__ dense_b,
    float* __restrict__ prm) {
  __shared__ float tv[8];
  int tid = threadIdx.x;
  if (tid < 8) {
    float s = 0.f;
    for (int j = 0; j < 43; j++) s += timeoh[j] * temb_w[j * 8 + tid];
    tv[tid] = s;
  }
  __syncthreads();
  if (tid < 64) {
    float s = 0.f;
    for (int d = 0; d < 8; d++) s += tv[d] * atten_pool[d * 64 + tid];
    prm[PRM_ATTN + tid] = s;
  }
  for (int idx = tid; idx < 1024; idx += 256) {
    int r = idx >> 5, c = idx & 31;
    float s = 0.f, s2 = 0.f;
    for (int d = 0; d < 192; d++) {
      s  += q_w[r * 192 + d] * k_w[c * 192 + d];    // G = q_w @ k_w^T
      s2 += v_w[r * 192 + d] * dense_w[d * 32 + c]; // H = v_w @ dense_w
    }
    prm[PRM_G + idx] = s;
    prm[PRM_H + idx] = s2;
  }
  if (tid < 32) {
    float s = 0.f, s2 = 0.f, s3 = 0.f;
    for (int d = 0; d < 192; d++) {
      s  += q_w[tid * 192 + d] * k_b[d];
      s2 += k_w[tid * 192 + d] * q_b[d];
      s3 += v_b[d] * dense_w[d * 32 + tid];
    }
    prm[PRM_G1 + tid] = s;
    prm[PRM_G2 + tid] = s2;
    prm[PRM_HB + tid] = s3 + dense_b[tid];
  }
  if (tid == 0) {
    float s = 0.f;
    for (int d = 0; d < 192; d++) s += q_b[d] * k_b[d];
    prm[PRM_G0] = s;
  }
}

// ---------------- h = x@mlp_w+mlp_b (bf16 out), s_src/s_dst = h . attn halves ----------
__global__ __launch_bounds__(256) void k_h(
    const float* __restrict__ x, const float* __restrict__ mlp_w,
    const float* __restrict__ mlp_b, const float* __restrict__ prm,
    __hip_bfloat16* __restrict__ h16, float* __restrict__ s_src,
    float* __restrict__ s_dst) {
  __shared__ float W[32 * 32];
  __shared__ float bsh[32], attnsh[64];
  __shared__ float xs[8][32];
  int tid = threadIdx.x;
  for (int i = tid; i < 1024; i += 256) W[i] = mlp_w[i];
  if (tid < 32) bsh[tid] = mlp_b[tid];
  if (tid < 64) attnsh[tid] = prm[PRM_ATTN + tid];
  long base = (long)blockIdx.x * 8;
  int nloc = tid >> 5, c = tid & 31;
  long row = base + nloc;  // flat t*N+n, grid sized exactly
  xs[nloc][c] = x[row * 32 + c];
  __syncthreads();
  float hval = bsh[c];
#pragma unroll
  for (int k = 0; k < 32; k++) hval = fmaf(xs[nloc][k], W[k * 32 + c], hval);
  h16[row * 32 + c] = __float2bfloat16(hval);
  float a = hval * attnsh[c], b = hval * attnsh[32 + c];
#pragma unroll
  for (int m = 16; m >= 1; m >>= 1) {
    a += __shfl_xor(a, m, 64);
    b += __shfl_xor(b, m, 64);
  }
  if (c == 0) { s_src[row] = a; s_dst[row] = b; }
}

// ---------------- per-t shift bound: M[t] = max_n ssrc + max_n sdst ---------------------
__global__ __launch_bounds__(256) void k_maxs(const float* __restrict__ ssrc,
                                              const float* __restrict__ sdst,
                                              float* __restrict__ Mt) {
  __shared__ float sh[8];
  const int t = blockIdx.x, tid = threadIdx.x;
  float ma = -1e30f, mb = -1e30f;
  for (int i = tid; i < N_; i += 256) {
    ma = fmaxf(ma, ssrc[(long)t * N_ + i]);
    mb = fmaxf(mb, sdst[(long)t * N_ + i]);
  }
#pragma unroll
  for (int k = 32; k >= 1; k >>= 1) {
    ma = fmaxf(ma, __shfl_xor(ma, k, 64));
    mb = fmaxf(mb, __shfl_xor(mb, k, 64));
  }
  if ((tid & 63) == 0) { sh[(tid >> 6) * 2] = ma; sh[(tid >> 6) * 2 + 1] = mb; }
  __syncthreads();
  if (tid == 0) {
    float A = fmaxf(fmaxf(sh[0], sh[2]), fmaxf(sh[4], sh[6]));
    float B = fmaxf(fmaxf(sh[1], sh[3]), fmaxf(sh[5], sh[7]));
    Mt[t] = A + B;
  }
}

// ---------------- CSR build ----------------
__global__ __launch_bounds__(256) void k_hist(const int* __restrict__ edges,
                                              int* __restrict__ cnt) {
  int sup = blockIdx.y;
  int e = blockIdx.x * 256 + threadIdx.x;
  const int* src = edges + (long)sup * 2 * E_;
  atomicAdd(&cnt[sup * N_ + src[e]], 1);
}

__global__ __launch_bounds__(1024) void k_scan(const int* __restrict__ cnt,
                                               int* __restrict__ offs,
                                               int* __restrict__ cur) {
  __shared__ int sh[1024];
  __shared__ int run;
  int sup = blockIdx.x, tid = threadIdx.x;
  if (tid == 0) run = 0;
  __syncthreads();
  for (int base = 0; base < N_; base += 1024) {
    int i = base + tid;
    int v = (i < N_) ? cnt[sup * N_ + i] : 0;
    sh[tid] = v;
    __syncthreads();
    for (int off = 1; off < 1024; off <<= 1) {
      int t = (tid >= off) ? sh[tid - off] : 0;
      __syncthreads();
      sh[tid] += t;
      __syncthreads();
    }
    int runv = run;
    int excl = runv + sh[tid] - v;
    if (i < N_) {
      offs[sup * (N_ + 1) + i] = excl;
      cur[sup * N_ + i] = excl;
    }
    __syncthreads();
    if (tid == 0) run = runv + sh[1023];
    __syncthreads();
  }
  if (tid == 0) offs[sup * (N_ + 1) + N_] = run;
}

__global__ __launch_bounds__(256) void k_fill(const int* __restrict__ edges,
                                              int* __restrict__ cur,
                                              int* __restrict__ csr) {
  int sup = blockIdx.y;
  int e = blockIdx.x * 256 + threadIdx.x;
  const int* src = edges + (long)sup * 2 * E_;
  const int* dst = src + E_;
  int pos = atomicAdd(&cur[sup * N_ + src[e]], 1);
  csr[sup * E_ + pos] = dst[e];
}

// ---------------- GAT gather v2: 16 edge-slots x 4 lanes (8 cols each via uint4) --------
__global__ __launch_bounds__(256) void k_gather(
    const int* __restrict__ csr, const int* __restrict__ offs,
    const float* __restrict__ s_src, const float* __restrict__ s_dst,
    const float* __restrict__ Mt, const __hip_bfloat16* __restrict__ h16,
    __hip_bfloat16* __restrict__ hp16) {
  const int sup = blockIdx.z, t = blockIdx.y;
  const int wave = threadIdx.x >> 6, lane = threadIdx.x & 63;
  const int n = blockIdx.x * 4 + wave;
  const float M = Mt[t];
  const float a = s_src[(long)t * N_ + n];
  const int off = offs[sup * (N_ + 1) + n], end = offs[sup * (N_ + 1) + n + 1];
  const float* sd = s_dst + (long)t * N_;
  const uint4* hb4 = (const uint4*)(h16 + (long)t * N_ * 32);
  const int* csrs = csr + sup * E_;
  const int slot = lane >> 2, cl = lane & 3;
  const int clamp = (end > off) ? (end - 1) : 0;

  float acc[8];
#pragma unroll
  for (int j = 0; j < 8; j++) acc[j] = 0.f;
  float psum = 0.f;

  const int idx0 = off + slot;
  int d0 = csrs[min(idx0, clamp)];
  int d1 = csrs[min(idx0 + 16, clamp)];
  float sd0 = sd[d0];
  uint4 u0 = hb4[d0 * 4 + cl];

  for (int idx = idx0; idx < end; idx += 16) {
    int d2 = csrs[min(idx + 32, clamp)];          // two ahead
    float sd1 = sd[d1];                           // one ahead
    uint4 u1 = hb4[d1 * 4 + cl];
    float v = a + sd0;
    v = fmaxf(v, 0.01f * v);                      // leaky
    float p = __expf(v - M);
    psum += p;
    acc[0] = fmaf(p, __uint_as_float(u0.x << 16),        acc[0]);
    acc[1] = fmaf(p, __uint_as_float(u0.x & 0xffff0000u), acc[1]);
    acc[2] = fmaf(p, __uint_as_float(u0.y << 16),        acc[2]);
    acc[3] = fmaf(p, __uint_as_float(u0.y & 0xffff0000u), acc[3]);
    acc[4] = fmaf(p, __uint_as_float(u0.z << 16),        acc[4]);
    acc[5] = fmaf(p, __uint_as_float(u0.z & 0xffff0000u), acc[5]);
    acc[6] = fmaf(p, __uint_as_float(u0.w << 16),        acc[6]);
    acc[7] = fmaf(p, __uint_as_float(u0.w & 0xffff0000u), acc[7]);
    d1 = d2; sd0 = sd1; u0 = u1;
  }

#pragma unroll
  for (int m = 4; m <= 32; m <<= 1) psum += __shfl_xor(psum, m, 64);
#pragma unroll
  for (int j = 0; j < 8; j++) {
#pragma unroll
    for (int m = 4; m <= 32; m <<= 1) acc[j] += __shfl_xor(acc[j], m, 64);
  }

  if (slot == 0) {  // lanes 0..3, each owns 8 contiguous cols (16B)
    float inv = 1.f / (psum + 9e-15f);
    unsigned w[4];
#pragma unroll
    for (int q = 0; q < 4; q++) {
      float h0 = acc[2 * q + 0] * inv;
      float h1 = acc[2 * q + 1] * inv;
      h0 = (h0 > 0.f) ? h0 : (__expf(h0) - 1.f);
      h1 = (h1 > 0.f) ? h1 : (__expf(h1) - 1.f);
      unsigned lo = (unsigned)(unsigned short)__builtin_bit_cast(unsigned short, __float2bfloat16(h0));
      unsigned hi = (unsigned)(unsigned short)__builtin_bit_cast(unsigned short, __float2bfloat16(h1));
      w[q] = lo | (hi << 16);
    }
    ((uint4*)hp16)[((long)sup * TN_ + (long)t * N_ + n) * 4 + cl] = uint4{w[0], w[1], w[2], w[3]};
  }
}

// ---------------- n2v -> bf16 frag-packed, PRE-SCALED by sqrt(log2 e) ------------------
__global__ __launch_bounds__(256) void k_n2vA(const float* __restrict__ n2v,
                                              short* __restrict__ n2vA) {
  const float SC = 1.2011224087864498f;  // sqrt(log2(e))
  int idx = blockIdx.x * 256 + threadIdx.x;
  if (idx >= N_ * 4) return;
  int row = idx >> 2, l4 = idx & 3;
  short v[8];
#pragma unroll
  for (int h = 0; h < 2; h++)
#pragma unroll
    for (int j = 0; j < 4; j++)
      v[h * 4 + j] = bf16c(n2v[row * 32 + 16 * h + 4 * l4 + j] * SC);
  *(bf16x8*)&n2vA[(long)idx * 8] = bf16x8{v[0], v[1], v[2], v[3], v[4], v[5], v[6], v[7]};
}

// ---------------- pack X (f32, optionally *rinv) into B-frag layout bf16 ---------------
template <int WITHR>
__global__ __launch_bounds__(256) void k_pack(const float* __restrict__ src,
                                              const float* __restrict__ rinv,
                                              short* __restrict__ xq) {
  int idx = blockIdx.x * 256 + threadIdx.x;  // 313*4*384 = 480768 exact
  int ck = idx / 1536;
  int rem = idx - ck * 1536;
  int l4 = rem / 384;
  int col = rem - l4 * 384;
  int t = col >> 5, f = col & 31;
  const long cb = (long)t * N_ * 32 + f;
  short v[8];
#pragma unroll
  for (int e = 0; e < 8; e++) {
    int vv = ck * 32 + 4 * l4 + (e & 3) + 16 * (e >> 2);
    float a = 0.f;
    if (vv < N_) {
      a = src[cb + (long)vv * 32];
      if (WITHR) a *= rinv[vv];
    }
    v[e] = bf16c(a);
  }
  *(bf16x8*)&xq[(long)idx * 8] = bf16x8{v[0], v[1], v[2], v[3], v[4], v[5], v[6], v[7]};
}

// ---------------- MFMA fused adj@X v14: DMA-staged xq + LDS-shared aP ------------------
// grid 157, 512 thr (8 waves), block = 64 rows x 384 cols, 1 block/CU.
// Groups of 2 chunks. xbuf[2][2*CHUNKB] double-buffer filled by global_load_lds (no VGPR
// round-trip, can't be compiler-sunk). Phase A(g+1): wave w = (chunk-slot wv>>2,
// Mtile wv&3) builds one aP -> slab. Phase B(g): per wave 6 bx ds_read_b128 + 8 aP
// ds_reads + 24 MFMA. One barrier per group drains the DMA (a full group to land).
template <int PASS>
__global__ __launch_bounds__(512, 2) void k_adj14(const short* __restrict__ n2vA,
                                                  const short* __restrict__ xq,
                                                  float* __restrict__ out,
                                                  float* __restrict__ Rout) {
  __shared__ __align__(16) char xbuf[2][2 * CHUNKB];      // 96 KB
  __shared__ __align__(16) short aPl[2][8 * 64 * 8];      // 16 KB (slot = wv = cslot*4+mt)
  const int tid = threadIdx.x;
  const int lane = tid & 63;
  const int wv = tid >> 6;        // 0..7
  const int l15 = lane & 15;
  const int l4 = lane >> 4;       // 0..3
  const int brow0 = blockIdx.x * 64;
  const int colbase = wv * 48;    // phase B colgroup
  const int amt = wv & 3;         // phase A Mtile

  // bw frag for phase A's single Mtile
  bf16x8 bwA;
  {
    int row = brow0 + amt * 16 + l15;
    row = row < N_ ? row : N_ - 1;
    bwA = *(const bf16x8*)&n2vA[((long)row * 4 + l4) * 8];
  }

  f32x4 acc[4][3];
#pragma unroll
  for (int i = 0; i < 4; i++)
#pragma unroll
    for (int j = 0; j < 3; j++) acc[i][j] = f32x4{0.f, 0.f, 0.f, 0.f};
  float raccA = 0.f;

  const int NGRP = 157;  // groups of 2 chunks; group 156 = chunk 312 only

#define STAGE(G, buf)                                                                     \
  {                                                                                       \
    const int sbytes = (2 * (G) + 1 < 313) ? 2 * CHUNKB : CHUNKB;                         \
    const char* src_ = (const char*)xq + (long)(G) * 2 * CHUNKB + wv * 6144 + lane * 16;  \
    char* dst_ = xbuf[buf] + wv * 6144;                                                   \
    _Pragma("unroll")                                                                     \
    for (int i = 0; i < 6; i++)                                                           \
      if (wv * 6144 + i * 1024 < sbytes) gload_lds16(src_ + i * 1024, dst_ + i * 1024);   \
  }

#define PHASE_A(G, slab)                                                                  \
  {                                                                                       \
    const int c_ = 2 * (G) + (wv >> 2);                                                   \
    if (c_ < 313) {                                                                       \
      const int vb_ = c_ * 32;                                                            \
      int r1_ = vb_ + 16 + l15; r1_ = r1_ < N_ ? r1_ : N_ - 1;                            \
      bf16x8 av0_ = *(const bf16x8*)&n2vA[((long)(vb_ + l15) * 4 + l4) * 8];              \
      bf16x8 av1_ = *(const bf16x8*)&n2vA[((long)r1_ * 4 + l4) * 8];                      \
      f32x4 s0_ = __builtin_amdgcn_mfma_f32_16x16x32_bf16(av0_, bwA,                      \
                                                          f32x4{0.f,0.f,0.f,0.f},0,0,0); \
      f32x4 s1_ = __builtin_amdgcn_mfma_f32_16x16x32_bf16(av1_, bwA,                      \
                                                          f32x4{0.f,0.f,0.f,0.f},0,0,0); \
      short pp_[8];                                                                       \
      float rs0_ = 0.f, rs1_ = 0.f;                                                       \
      _Pragma("unroll")                                                                   \
      for (int j = 0; j < 4; j++) {                                                       \
        float p0_ = EXP2F(fmaxf(s0_[j], 0.f));                                            \
        float p1_ = EXP2F(fmaxf(s1_[j], 0.f));                                            \
        if constexpr (PASS == 1) { rs0_ += p0_; rs1_ += p1_; }                            \
        pp_[j] = bf16c(p0_);                                                              \
        pp_[j + 4] = bf16c(p1_);                                                          \
      }                                                                                   \
      *(bf16x8*)&aPl[slab][(wv * 64 + lane) * 8] =                                        \
          bf16x8{pp_[0],pp_[1],pp_[2],pp_[3],pp_[4],pp_[5],pp_[6],pp_[7]};                \
      if constexpr (PASS == 1) raccA += (c_ != 312) ? (rs0_ + rs1_) : rs0_;               \
    }                                                                                     \
  }

  // prologue: stage + phase A for group 0
  STAGE(0, 0)
  PHASE_A(0, 0)
  __syncthreads();

  for (int g = 0; g < NGRP; g++) {
    const int cur = g & 1;
    if (g + 1 < NGRP) {
      STAGE(g + 1, cur ^ 1)
      PHASE_A(g + 1, cur ^ 1)
    }
    // ---- phase B: consume group g from LDS ----
#pragma unroll
    for (int cc = 0; cc < 2; cc++) {
      if (2 * g + cc >= 313) break;
      const char* xb = xbuf[cur] + cc * CHUNKB;
      bf16x8 bx0 = *(const bf16x8*)(xb + (l4 * 384 + colbase + 0 * 16 + l15) * 16);
      bf16x8 bx1 = *(const bf16x8*)(xb + (l4 * 384 + colbase + 1 * 16 + l15) * 16);
      bf16x8 bx2 = *(const bf16x8*)(xb + (l4 * 384 + colbase + 2 * 16 + l15) * 16);
#pragma unroll
      for (int mt = 0; mt < 4; mt++) {
        bf16x8 aP = *(const bf16x8*)&aPl[cur][((cc * 4 + mt) * 64 + lane) * 8];
        acc[mt][0] = __builtin_amdgcn_mfma_f32_16x16x32_bf16(aP, bx0, acc[mt][0], 0, 0, 0);
        acc[mt][1] = __builtin_amdgcn_mfma_f32_16x16x32_bf16(aP, bx1, acc[mt][1], 0, 0, 0);
        acc[mt][2] = __builtin_amdgcn_mfma_f32_16x16x32_bf16(aP, bx2, acc[mt][2], 0, 0, 0);
      }
    }
    __syncthreads();  // drains stage DMA + protects slabs/xbuf swap
  }
#undef PHASE_A
#undef STAGE

  // R: phase-A wave holds partials for Mtile amt (chunks of its cslot); atomicAdd merge
  if constexpr (PASS == 1) {
    float r = raccA;
    r += __shfl_xor(r, 16, 64);
    r += __shfl_xor(r, 32, 64);
    int w = brow0 + amt * 16 + l15;
    if (l4 == 0 && w < N_) atomicAdd(&Rout[w], r);
  }
  // plain stores: (block,wave) owns 64 rows x its 48 cols exclusively
#pragma unroll
  for (int mt = 0; mt < 4; mt++) {
#pragma unroll
    for (int nt = 0; nt < 3; nt++) {
      const int col = colbase + nt * 16 + l15;
      const int t = col >> 5, f = col & 31;
#pragma unroll
      for (int j = 0; j < 4; j++) {
        const int w = brow0 + mt * 16 + 4 * l4 + j;
        if (w < N_) out[((long)t * N_ + w) * 32 + f] = acc[mt][nt][j];
      }
    }
  }
}

__global__ __launch_bounds__(256) void k_rinv(float* __restrict__ R) {
  int i = blockIdx.x * 256 + threadIdx.x;
  if (i < N_) R[i] = 1.f / R[i];
}

// ---------------- x_adp = [x, x1/R, x2/R] @ gcn_w + gcn_b   (in-place over x2) --------
__global__ __launch_bounds__(256) void k_gcn(const float* __restrict__ x,
                                             const float* __restrict__ x1,
                                             float* __restrict__ x2io,
                                             const float* __restrict__ Rinv,
                                             const float* __restrict__ gcn_w,
                                             const float* __restrict__ gcn_b) {
  __shared__ float W[96 * 32];
  __shared__ float bsh[32];
  __shared__ float rows[8][96];
  int tid = threadIdx.x;
  for (int i = tid; i < 96 * 32; i += 256) W[i] = gcn_w[i];
  if (tid < 32) bsh[tid] = gcn_b[tid];
  long base = (long)blockIdx.x * 8;
  int nloc = tid >> 5, c = tid & 31;
  long row = base + nloc;
  long nIdx = row % N_;
  float ri = Rinv[nIdx];
  rows[nloc][c] = x[row * 32 + c];
  rows[nloc][32 + c] = x1[row * 32 + c] * ri;
  rows[nloc][64 + c] = x2io[row * 32 + c] * ri;
  __syncthreads();
  float o = bsh[c];
#pragma unroll
  for (int k = 0; k < 96; k++) o = fmaf(rows[nloc][k], W[k * 32 + c], o);
  __syncthreads();
  x2io[row * 32 + c] = o;
}

// ---------------- collapsed slot attention v3: SHUFFLE-FREE, lane-owns-dot -------------
__global__ __launch_bounds__(256) void k_attn3(const float* __restrict__ x,
                                               const __hip_bfloat16* __restrict__ hp16,
                                               const float* __restrict__ xadp,
                                               const float* __restrict__ prm,
                                               float* __restrict__ out) {
  __shared__ float Gs[1024], Hs[1024], g1s[32], g2s[32], hbs[32];
  __shared__ float g0sh;
  __shared__ float msl[8][5][33];
  __shared__ float yl[8][5][33];
  __shared__ float scl[8][33];
  __shared__ float zl[8][33];
  const int tid = threadIdx.x;
  const int nloc = tid >> 5, c = tid & 31;
  for (int i = tid; i < 1024; i += 256) { Gs[i] = prm[PRM_G + i]; Hs[i] = prm[PRM_H + i]; }
  if (tid < 32) { g1s[tid] = prm[PRM_G1 + tid]; g2s[tid] = prm[PRM_G2 + tid]; hbs[tid] = prm[PRM_HB + tid]; }
  if (tid == 0) g0sh = prm[PRM_G0];
  const long r = (long)blockIdx.x * 8 + nloc;  // grid sized exactly: 15000 * 8 = TN_
  msl[nloc][0][c] = x[r * 32 + c];
#pragma unroll
  for (int s = 1; s <= 3; s++)
    msl[nloc][s][c] = __bfloat162float(hp16[((long)(s - 1) * TN_ + r) * 32 + c]);
  msl[nloc][4][c] = xadp[r * 32 + c];
  __syncthreads();

  // y-pass: ytilde[s][c] = sum_k m_s[k] G[k][c] + g2[c]
#pragma unroll
  for (int s = 0; s < 5; s++) {
    float y = 0.f;
#pragma unroll
    for (int k = 0; k < 32; k++) y = fmaf(msl[nloc][s][k], Gs[k * 32 + c], y);
    yl[nloc][s][c] = y + g2s[c];
  }
  // dot-pass (wave-synchronous within the team)
  {
    float dot = 0.f;
    if (c < 25) {
      const int s = c / 5, u = c - s * 5;
#pragma unroll
      for (int k = 0; k < 32; k++) dot = fmaf(yl[nloc][s][k], msl[nloc][u][k], dot);
    } else if (c < 30) {
      const int u = c - 25;
#pragma unroll
      for (int k = 0; k < 32; k++) dot = fmaf(msl[nloc][u][k], g1s[k], dot);
    }
    scl[nloc][c] = dot;
  }

  const float rs = 0.07216878364870322f;  // 1/sqrt(192)
  const float g0 = g0sh;
  float abar[5];
#pragma unroll
  for (int u = 0; u < 5; u++) abar[u] = 0.f;
#pragma unroll
  for (int s = 0; s < 5; s++) {
    const float d1s = scl[nloc][25 + s];
    float e[5];
    float mx = -1e30f;
#pragma unroll
    for (int u = 0; u < 5; u++) {
      float v = (scl[nloc][s * 5 + u] + d1s + g0) * rs;
      e[u] = v;
      mx = fmaxf(mx, v);
    }
    float sm = 0.f;
#pragma unroll
    for (int u = 0; u < 5; u++) { e[u] = __expf(e[u] - mx); sm += e[u]; }
    float inv = 1.f / sm;
#pragma unroll
    for (int u = 0; u < 5; u++) abar[u] = fmaf(e[u], inv, abar[u]);
  }

  float z = 0.f;
#pragma unroll
  for (int u = 0; u < 5; u++) z = fmaf(abar[u], msl[nloc][u][c], z);
  zl[nloc][c] = z * 0.2f;

  float o = hbs[c];
#pragma unroll
  for (int k = 0; k < 32; k++) o = fmaf(zl[nloc][k], Hs[k * 32 + c], o);
  o = (o > 0.f) ? o : (__expf(o) - 1.f);
  out[r * 32 + c] = o;
}

// ---------------- launch ----------------
extern "C" void kernel_launch(void* const* d_in, const int* in_sizes, int n_in,
                              void* d_out, int out_size, void* d_ws, size_t ws_size,
                              hipStream_t stream) {
  (void)in_sizes; (void)n_in; (void)out_size; (void)ws_size;
  const float* x          = (const float*)d_in[0];
  const float* timeoh     = (const float*)d_in[1];
  const int*   edges      = (const int*)d_in[2];
  const float* mlp_w      = (const float*)d_in[3];
  const float* mlp_b      = (const float*)d_in[4];
  const float* temb_w     = (const float*)d_in[5];
  const float* atten_pool = (const float*)d_in[6];
  const float* node2vec   = (const float*)d_in[7];
  const float* gcn_w      = (const float*)d_in[8];
  const float* gcn_b      = (const float*)d_in[9];
  const float* q_w  = (const float*)d_in[10];
  const float* q_b  = (const float*)d_in[11];
  const float* k_w  = (const float*)d_in[12];
  const float* k_b  = (const float*)d_in[13];
  const float* v_w  = (const float*)d_in[14];
  const float* v_b  = (const float*)d_in[15];
  const float* dense_w = (const float*)d_in[16];
  const float* dense_b = (const float*)d_in[17];
  float* out = (float*)d_out;
  char* ws = (char*)d_ws;

  float*    prm  = (float*)(ws + 0);
  float*    Mt   = (float*)(ws + 9216);
  int*      cnt  = (int*)(ws + 9472);
  int*      cur  = (int*)(ws + 129472);
  int*      offs = (int*)(ws + 249472);
  float*    ssrc = (float*)(ws + 369664);
  float*    sdst = (float*)(ws + 849664);
  float*    R    = (float*)(ws + 1329664);
  __hip_bfloat16* h16  = (__hip_bfloat16*)(ws + 1369664);
  int*      csr  = (int*)(ws + 9049664);
  __hip_bfloat16* hp16 = (__hip_bfloat16*)(ws + 12889664);
  float*    x1   = (float*)(ws + 35929664);
  float*    x2   = (float*)(ws + 51289664);
  short*    n2vA = (short*)(ws + 66649664);   //   640,000 B
  short*    xq0  = (short*)(ws + 67289664);   // 7,692,288 B
  short*    xq1  = (short*)(ws + 74983488);   // 7,692,288 B

  (void)hipMemsetAsync(cnt, 0, 120000, stream);
  (void)hipMemsetAsync(R, 0, 40000, stream);

  k_prep<<<1, 256, 0, stream>>>(timeoh, temb_w, atten_pool, q_w, q_b, k_w, k_b,
                                v_w, v_b, dense_w, dense_b, prm);
  k_h<<<15000, 256, 0, stream>>>(x, mlp_w, mlp_b, prm, h16, ssrc, sdst);
  k_maxs<<<12, 256, 0, stream>>>(ssrc, sdst, Mt);
  k_hist<<<dim3(1250, 3), 256, 0, stream>>>(edges, cnt);
  k_scan<<<3, 1024, 0, stream>>>(cnt, offs, cur);
  k_fill<<<dim3(1250, 3), 256, 0, stream>>>(edges, cur, csr);
  k_gather<<<dim3(2500, 12, 3), 256, 0, stream>>>(csr, offs, ssrc, sdst, Mt, h16, hp16);

  k_n2vA<<<157, 256, 0, stream>>>(node2vec, n2vA);
  k_pack<0><<<1878, 256, 0, stream>>>(x, nullptr, xq0);
  k_adj14<1><<<157, 512, 0, stream>>>(n2vA, xq0, x1, R);
  k_rinv<<<40, 256, 0, stream>>>(R);
  k_pack<1><<<1878, 256, 0, stream>>>(x1, R, xq1);
  k_adj14<2><<<157, 512, 0, stream>>>(n2vA, xq1, x2, nullptr);
  k_gcn<<<15000, 256, 0, stream>>>(x, x1, x2, R, gcn_w, gcn_b);
  k_attn3<<<15000, 256, 0, stream>>>(x, hp16, x2, prm, out);
}

// Round 22
// 843.198 us; speedup vs baseline: 1.2119x; 1.2119x over previous
//
#include <hip/hip_runtime.h>
#include <hip/hip_bf16.h>

#define T_ 12
#define N_ 10000
#define C_ 32
#define E_ 320000
#define SUP_ 3
#define TN_ (T_*N_)

typedef __attribute__((ext_vector_type(4))) float f32x4;
typedef __attribute__((ext_vector_type(8))) short bf16x8;
typedef __attribute__((ext_vector_type(4))) short bf16x4;

__device__ __forceinline__ short bf16c(float f) {
  __hip_bfloat16 b = __float2bfloat16(f);
  return (short)__builtin_bit_cast(unsigned short, b);
}

#if __has_builtin(__builtin_amdgcn_exp2f)
#define EXP2F(x) __builtin_amdgcn_exp2f(x)
#else
#define EXP2F(x) exp2f(x)
#endif

// prm layout (float offsets)
#define PRM_ATTN 0
#define PRM_G    64
#define PRM_H    1088
#define PRM_G1   2112
#define PRM_G2   2144
#define PRM_HB   2176
#define PRM_G0   2208

// ---------------- small precompute: attn vector + folded attention mats ----------------
__global__ __launch_bounds__(256) void k_prep(
    const float* __restrict__ timeoh, const float* __restrict__ temb_w,
    const float* __restrict__ atten_pool,
    const float* __restrict__ q_w, const float* __restrict__ q_b,
    const float* __restrict__ k_w, const float* __restrict__ k_b,
    const float* __restrict__ v_w, const float* __restrict__ v_b,
    const float* __restrict__ dense_w, const float* __restrict__ dense_b,
    float* __restrict__ prm) {
  __shared__ float tv[8];
  int tid = threadIdx.x;
  if (tid < 8) {
    float s = 0.f;
    for (int j = 0; j < 43; j++) s += timeoh[j] * temb_w[j * 8 + tid];
    tv[tid] = s;
  }
  __syncthreads();
  if (tid < 64) {
    float s = 0.f;
    for (int d = 0; d < 8; d++) s += tv[d] * atten_pool[d * 64 + tid];
    prm[PRM_ATTN + tid] = s;
  }
  for (int idx = tid; idx < 1024; idx += 256) {
    int r = idx >> 5, c = idx & 31;
    float s = 0.f, s2 = 0.f;
    for (int d = 0; d < 192; d++) {
      s  += q_w[r * 192 + d] * k_w[c * 192 + d];    // G = q_w @ k_w^T
      s2 += v_w[r * 192 + d] * dense_w[d * 32 + c]; // H = v_w @ dense_w
    }
    prm[PRM_G + idx] = s;
    prm[PRM_H + idx] = s2;
  }
  if (tid < 32) {
    float s = 0.f, s2 = 0.f, s3 = 0.f;
    for (int d = 0; d < 192; d++) {
      s  += q_w[tid * 192 + d] * k_b[d];
      s2 += k_w[tid * 192 + d] * q_b[d];
      s3 += v_b[d] * dense_w[d * 32 + tid];
    }
    prm[PRM_G1 + tid] = s;
    prm[PRM_G2 + tid] = s2;
    prm[PRM_HB + tid] = s3 + dense_b[tid];
  }
  if (tid == 0) {
    float s = 0.f;
    for (int d = 0; d < 192; d++) s += q_b[d] * k_b[d];
    prm[PRM_G0] = s;
  }
}

// ---------------- h = x@mlp_w+mlp_b (bf16 out), s_src/s_dst = h . attn halves ----------
__global__ __launch_bounds__(256) void k_h(
    const float* __restrict__ x, const float* __restrict__ mlp_w,
    const float* __restrict__ mlp_b, const float* __restrict__ prm,
    __hip_bfloat16* __restrict__ h16, float* __restrict__ s_src,
    float* __restrict__ s_dst) {
  __shared__ float W[32 * 32];
  __shared__ float bsh[32], attnsh[64];
  __shared__ float xs[8][32];
  int tid = threadIdx.x;
  for (int i = tid; i < 1024; i += 256) W[i] = mlp_w[i];
  if (tid < 32) bsh[tid] = mlp_b[tid];
  if (tid < 64) attnsh[tid] = prm[PRM_ATTN + tid];
  long base = (long)blockIdx.x * 8;
  int nloc = tid >> 5, c = tid & 31;
  long row = base + nloc;  // flat t*N+n, grid sized exactly
  xs[nloc][c] = x[row * 32 + c];
  __syncthreads();
  float hval = bsh[c];
#pragma unroll
  for (int k = 0; k < 32; k++) hval = fmaf(xs[nloc][k], W[k * 32 + c], hval);
  h16[row * 32 + c] = __float2bfloat16(hval);
  float a = hval * attnsh[c], b = hval * attnsh[32 + c];
#pragma unroll
  for (int m = 16; m >= 1; m >>= 1) {
    a += __shfl_xor(a, m, 64);
    b += __shfl_xor(b, m, 64);
  }
  if (c == 0) { s_src[row] = a; s_dst[row] = b; }
}

// ---------------- per-t shift bound: M[t] = max_n ssrc + max_n sdst ---------------------
// Any per-t constant shift cancels exactly in h' = sum(e*h)/sum(e); this bound >= true
// max so exp stays <= 1. Replaces the 36-edge-sweep k_max.
__global__ __launch_bounds__(256) void k_maxs(const float* __restrict__ ssrc,
                                              const float* __restrict__ sdst,
                                              float* __restrict__ Mt) {
  __shared__ float sh[8];
  const int t = blockIdx.x, tid = threadIdx.x;
  float ma = -1e30f, mb = -1e30f;
  for (int i = tid; i < N_; i += 256) {
    ma = fmaxf(ma, ssrc[(long)t * N_ + i]);
    mb = fmaxf(mb, sdst[(long)t * N_ + i]);
  }
#pragma unroll
  for (int k = 32; k >= 1; k >>= 1) {
    ma = fmaxf(ma, __shfl_xor(ma, k, 64));
    mb = fmaxf(mb, __shfl_xor(mb, k, 64));
  }
  if ((tid & 63) == 0) { sh[(tid >> 6) * 2] = ma; sh[(tid >> 6) * 2 + 1] = mb; }
  __syncthreads();
  if (tid == 0) {
    float A = fmaxf(fmaxf(sh[0], sh[2]), fmaxf(sh[4], sh[6]));
    float B = fmaxf(fmaxf(sh[1], sh[3]), fmaxf(sh[5], sh[7]));
    Mt[t] = A + B;
  }
}

// ---------------- CSR build ----------------
__global__ __launch_bounds__(256) void k_hist(const int* __restrict__ edges,
                                              int* __restrict__ cnt) {
  int sup = blockIdx.y;
  int e = blockIdx.x * 256 + threadIdx.x;
  const int* src = edges + (long)sup * 2 * E_;
  atomicAdd(&cnt[sup * N_ + src[e]], 1);
}

__global__ __launch_bounds__(1024) void k_scan(const int* __restrict__ cnt,
                                               int* __restrict__ offs,
                                               int* __restrict__ cur) {
  __shared__ int sh[1024];
  __shared__ int run;
  int sup = blockIdx.x, tid = threadIdx.x;
  if (tid == 0) run = 0;
  __syncthreads();
  for (int base = 0; base < N_; base += 1024) {
    int i = base + tid;
    int v = (i < N_) ? cnt[sup * N_ + i] : 0;
    sh[tid] = v;
    __syncthreads();
    for (int off = 1; off < 1024; off <<= 1) {
      int t = (tid >= off) ? sh[tid - off] : 0;
      __syncthreads();
      sh[tid] += t;
      __syncthreads();
    }
    int runv = run;
    int excl = runv + sh[tid] - v;
    if (i < N_) {
      offs[sup * (N_ + 1) + i] = excl;
      cur[sup * N_ + i] = excl;
    }
    __syncthreads();
    if (tid == 0) run = runv + sh[1023];
    __syncthreads();
  }
  if (tid == 0) offs[sup * (N_ + 1) + N_] = run;
}

__global__ __launch_bounds__(256) void k_fill(const int* __restrict__ edges,
                                              int* __restrict__ cur,
                                              int* __restrict__ csr) {
  int sup = blockIdx.y;
  int e = blockIdx.x * 256 + threadIdx.x;
  const int* src = edges + (long)sup * 2 * E_;
  const int* dst = src + E_;
  int pos = atomicAdd(&cur[sup * N_ + src[e]], 1);
  csr[sup * E_ + pos] = dst[e];
}

// ---------------- GAT gather v2: 16 edge-slots x 4 lanes (8 cols each via uint4) --------
__global__ __launch_bounds__(256) void k_gather(
    const int* __restrict__ csr, const int* __restrict__ offs,
    const float* __restrict__ s_src, const float* __restrict__ s_dst,
    const float* __restrict__ Mt, const __hip_bfloat16* __restrict__ h16,
    __hip_bfloat16* __restrict__ hp16) {
  const int sup = blockIdx.z, t = blockIdx.y;
  const int wave = threadIdx.x >> 6, lane = threadIdx.x & 63;
  const int n = blockIdx.x * 4 + wave;
  const float M = Mt[t];
  const float a = s_src[(long)t * N_ + n];
  const int off = offs[sup * (N_ + 1) + n], end = offs[sup * (N_ + 1) + n + 1];
  const float* sd = s_dst + (long)t * N_;
  const uint4* hb4 = (const uint4*)(h16 + (long)t * N_ * 32);
  const int* csrs = csr + sup * E_;
  const int slot = lane >> 2, cl = lane & 3;
  const int clamp = (end > off) ? (end - 1) : 0;

  float acc[8];
#pragma unroll
  for (int j = 0; j < 8; j++) acc[j] = 0.f;
  float psum = 0.f;

  const int idx0 = off + slot;
  int d0 = csrs[min(idx0, clamp)];
  int d1 = csrs[min(idx0 + 16, clamp)];
  float sd0 = sd[d0];
  uint4 u0 = hb4[d0 * 4 + cl];

  for (int idx = idx0; idx < end; idx += 16) {
    int d2 = csrs[min(idx + 32, clamp)];          // two ahead
    float sd1 = sd[d1];                           // one ahead
    uint4 u1 = hb4[d1 * 4 + cl];
    float v = a + sd0;
    v = fmaxf(v, 0.01f * v);                      // leaky
    float p = __expf(v - M);
    psum += p;
    acc[0] = fmaf(p, __uint_as_float(u0.x << 16),        acc[0]);
    acc[1] = fmaf(p, __uint_as_float(u0.x & 0xffff0000u), acc[1]);
    acc[2] = fmaf(p, __uint_as_float(u0.y << 16),        acc[2]);
    acc[3] = fmaf(p, __uint_as_float(u0.y & 0xffff0000u), acc[3]);
    acc[4] = fmaf(p, __uint_as_float(u0.z << 16),        acc[4]);
    acc[5] = fmaf(p, __uint_as_float(u0.z & 0xffff0000u), acc[5]);
    acc[6] = fmaf(p, __uint_as_float(u0.w << 16),        acc[6]);
    acc[7] = fmaf(p, __uint_as_float(u0.w & 0xffff0000u), acc[7]);
    d1 = d2; sd0 = sd1; u0 = u1;
  }

#pragma unroll
  for (int m = 4; m <= 32; m <<= 1) psum += __shfl_xor(psum, m, 64);
#pragma unroll
  for (int j = 0; j < 8; j++) {
#pragma unroll
    for (int m = 4; m <= 32; m <<= 1) acc[j] += __shfl_xor(acc[j], m, 64);
  }

  if (slot == 0) {  // lanes 0..3, each owns 8 contiguous cols (16B)
    float inv = 1.f / (psum + 9e-15f);
    unsigned w[4];
#pragma unroll
    for (int q = 0; q < 4; q++) {
      float h0 = acc[2 * q + 0] * inv;
      float h1 = acc[2 * q + 1] * inv;
      h0 = (h0 > 0.f) ? h0 : (__expf(h0) - 1.f);
      h1 = (h1 > 0.f) ? h1 : (__expf(h1) - 1.f);
      unsigned lo = (unsigned)(unsigned short)__builtin_bit_cast(unsigned short, __float2bfloat16(h0));
      unsigned hi = (unsigned)(unsigned short)__builtin_bit_cast(unsigned short, __float2bfloat16(h1));
      w[q] = lo | (hi << 16);
    }
    ((uint4*)hp16)[((long)sup * TN_ + (long)t * N_ + n) * 4 + cl] = uint4{w[0], w[1], w[2], w[3]};
  }
}

// ---------------- n2v -> bf16 frag-packed, PRE-SCALED by sqrt(log2 e) ------------------
__global__ __launch_bounds__(256) void k_n2vA(const float* __restrict__ n2v,
                                              short* __restrict__ n2vA) {
  const float SC = 1.2011224087864498f;  // sqrt(log2(e))
  int idx = blockIdx.x * 256 + threadIdx.x;
  if (idx >= N_ * 4) return;
  int row = idx >> 2, l4 = idx & 3;
  short v[8];
#pragma unroll
  for (int h = 0; h < 2; h++)
#pragma unroll
    for (int j = 0; j < 4; j++)
      v[h * 4 + j] = bf16c(n2v[row * 32 + 16 * h + 4 * l4 + j] * SC);
  *(bf16x8*)&n2vA[(long)idx * 8] = bf16x8{v[0], v[1], v[2], v[3], v[4], v[5], v[6], v[7]};
}

// ---------------- pack X (f32, optionally *rinv) into B-frag layout bf16 ---------------
template <int WITHR>
__global__ __launch_bounds__(256) void k_pack(const float* __restrict__ src,
                                              const float* __restrict__ rinv,
                                              short* __restrict__ xq) {
  int idx = blockIdx.x * 256 + threadIdx.x;  // 313*4*384 = 480768 exact
  int ck = idx / 1536;
  int rem = idx - ck * 1536;
  int l4 = rem / 384;
  int col = rem - l4 * 384;
  int t = col >> 5, f = col & 31;
  const long cb = (long)t * N_ * 32 + f;
  short v[8];
#pragma unroll
  for (int e = 0; e < 8; e++) {
    int vv = ck * 32 + 4 * l4 + (e & 3) + 16 * (e >> 2);
    float a = 0.f;
    if (vv < N_) {
      a = src[cb + (long)vv * 32];
      if (WITHR) a *= rinv[vv];
    }
    v[e] = bf16c(a);
  }
  *(bf16x8*)&xq[(long)idx * 8] = bf16x8{v[0], v[1], v[2], v[3], v[4], v[5], v[6], v[7]};
}

// ---------------- MFMA fused adj@X: LDS-shared aP, PING-PONG slabs, batched bx ---------
// (adj12 geometry — best measured: 175 us/pass.)
// grid 157, 512 thr (8 waves), block = 64 rows x 384 cols, 1 block/CU.
// Iteration g: phase A builds aP for group g+1 into slab[(g+1)&1] (wave w owns one
// chunk, all 4 Mtiles); phase B consumes group g from slab[g&1]: ALL 24 bx loads
// batch-issued first (24-deep MLP), then 96 main MFMAs. ONE barrier per group.
template <int PASS>
__global__ __launch_bounds__(512, 2) void k_adj12(const short* __restrict__ n2vA,
                                                  const short* __restrict__ xq,
                                                  float* __restrict__ out,
                                                  float* __restrict__ Rout) {
  __shared__ __align__(16) short aPl[2][8 * 4 * 64 * 8];  // 2 x 32 KB ping-pong
  const int tid = threadIdx.x;
  const int lane = tid & 63;
  const int wv = tid >> 6;       // 0..7 : colgroup in phase B, chunk-slot in phase A
  const int l15 = lane & 15;
  const int l4 = lane >> 4;      // 0..3
  const int brow0 = blockIdx.x * 64;
  const int colbase = wv * 48;

  bf16x8 bw[4];
#pragma unroll
  for (int mt = 0; mt < 4; mt++) {
    int row = brow0 + mt * 16 + l15;
    row = row < N_ ? row : N_ - 1;
    bw[mt] = *(const bf16x8*)&n2vA[((long)row * 4 + l4) * 8];
  }

  f32x4 acc[4][3];
#pragma unroll
  for (int i = 0; i < 4; i++)
#pragma unroll
    for (int j = 0; j < 3; j++) acc[i][j] = f32x4{0.f, 0.f, 0.f, 0.f};
  float racc[4] = {0.f, 0.f, 0.f, 0.f};

#define PHASE_A(cexpr, slab)                                                              \
  {                                                                                       \
    const int c_ = (cexpr);                                                               \
    if (c_ < 313) {                                                                       \
      const int vb_ = c_ * 32;                                                            \
      int r1_ = vb_ + 16 + l15; r1_ = r1_ < N_ ? r1_ : N_ - 1;                            \
      bf16x8 av0_ = *(const bf16x8*)&n2vA[((long)(vb_ + l15) * 4 + l4) * 8];              \
      bf16x8 av1_ = *(const bf16x8*)&n2vA[((long)r1_ * 4 + l4) * 8];                      \
      _Pragma("unroll")                                                                   \
      for (int mt = 0; mt < 4; mt++) {                                                    \
        f32x4 s0_ = __builtin_amdgcn_mfma_f32_16x16x32_bf16(av0_, bw[mt],                 \
                                                            f32x4{0.f,0.f,0.f,0.f},0,0,0);\
        f32x4 s1_ = __builtin_amdgcn_mfma_f32_16x16x32_bf16(av1_, bw[mt],                 \
                                                            f32x4{0.f,0.f,0.f,0.f},0,0,0);\
        short pp_[8];                                                                     \
        float rs0_ = 0.f, rs1_ = 0.f;                                                     \
        _Pragma("unroll")                                                                 \
        for (int j = 0; j < 4; j++) {                                                     \
          float p0_ = EXP2F(fmaxf(s0_[j], 0.f));                                          \
          float p1_ = EXP2F(fmaxf(s1_[j], 0.f));                                          \
          if constexpr (PASS == 1) { rs0_ += p0_; rs1_ += p1_; }                          \
          pp_[j] = bf16c(p0_);                                                            \
          pp_[j + 4] = bf16c(p1_);                                                        \
        }                                                                                 \
        *(bf16x8*)&aPl[slab][((wv * 4 + mt) * 64 + lane) * 8] =                           \
            bf16x8{pp_[0],pp_[1],pp_[2],pp_[3],pp_[4],pp_[5],pp_[6],pp_[7]};              \
        if constexpr (PASS == 1) racc[mt] += (c_ != 312) ? (rs0_ + rs1_) : rs0_;          \
      }                                                                                   \
    }                                                                                     \
  }

  PHASE_A(wv, 0)
  __syncthreads();

  for (int g = 0; g < 40; g++) {
    const int cur = g & 1;
    if (g + 1 < 40) PHASE_A((g + 1) * 8 + wv, cur ^ 1)

    const int rem = 313 - g * 8;
    if (rem >= 8) {
      bf16x8 bx[24];
#pragma unroll
      for (int cc = 0; cc < 8; cc++) {
        const long xb = (long)(g * 8 + cc) * 1536 + (long)l4 * 384;
        bx[cc * 3 + 0] = *(const bf16x8*)&xq[(xb + colbase + 0 * 16 + l15) * 8];
        bx[cc * 3 + 1] = *(const bf16x8*)&xq[(xb + colbase + 1 * 16 + l15) * 8];
        bx[cc * 3 + 2] = *(const bf16x8*)&xq[(xb + colbase + 2 * 16 + l15) * 8];
      }
#pragma unroll
      for (int cc = 0; cc < 8; cc++) {
#pragma unroll
        for (int mt = 0; mt < 4; mt++) {
          bf16x8 aP = *(const bf16x8*)&aPl[cur][((cc * 4 + mt) * 64 + lane) * 8];
          acc[mt][0] = __builtin_amdgcn_mfma_f32_16x16x32_bf16(aP, bx[cc * 3 + 0], acc[mt][0], 0, 0, 0);
          acc[mt][1] = __builtin_amdgcn_mfma_f32_16x16x32_bf16(aP, bx[cc * 3 + 1], acc[mt][1], 0, 0, 0);
          acc[mt][2] = __builtin_amdgcn_mfma_f32_16x16x32_bf16(aP, bx[cc * 3 + 2], acc[mt][2], 0, 0, 0);
        }
      }
    } else {
      for (int cc = 0; cc < rem; cc++) {
        const long xb = (long)(g * 8 + cc) * 1536 + (long)l4 * 384;
        bf16x8 bx0 = *(const bf16x8*)&xq[(xb + colbase + 0 * 16 + l15) * 8];
        bf16x8 bx1 = *(const bf16x8*)&xq[(xb + colbase + 1 * 16 + l15) * 8];
        bf16x8 bx2 = *(const bf16x8*)&xq[(xb + colbase + 2 * 16 + l15) * 8];
#pragma unroll
        for (int mt = 0; mt < 4; mt++) {
          bf16x8 aP = *(const bf16x8*)&aPl[cur][((cc * 4 + mt) * 64 + lane) * 8];
          acc[mt][0] = __builtin_amdgcn_mfma_f32_16x16x32_bf16(aP, bx0, acc[mt][0], 0, 0, 0);
          acc[mt][1] = __builtin_amdgcn_mfma_f32_16x16x32_bf16(aP, bx1, acc[mt][1], 0, 0, 0);
          acc[mt][2] = __builtin_amdgcn_mfma_f32_16x16x32_bf16(aP, bx2, acc[mt][2], 0, 0, 0);
        }
      }
    }
    __syncthreads();
  }
#undef PHASE_A

  if constexpr (PASS == 1) {
#pragma unroll
    for (int mt = 0; mt < 4; mt++) {
      float r = racc[mt];
      r += __shfl_xor(r, 16, 64);
      r += __shfl_xor(r, 32, 64);
      int w = brow0 + mt * 16 + l15;
      if (l4 == 0 && w < N_) atomicAdd(&Rout[w], r);
    }
  }
#pragma unroll
  for (int mt = 0; mt < 4; mt++) {
#pragma unroll
    for (int nt = 0; nt < 3; nt++) {
      const int col = colbase + nt * 16 + l15;
      const int t = col >> 5, f = col & 31;
#pragma unroll
      for (int j = 0; j < 4; j++) {
        const int w = brow0 + mt * 16 + 4 * l4 + j;
        if (w < N_) out[((long)t * N_ + w) * 32 + f] = acc[mt][nt][j];
      }
    }
  }
}

__global__ __launch_bounds__(256) void k_rinv(float* __restrict__ R) {
  int i = blockIdx.x * 256 + threadIdx.x;
  if (i < N_) R[i] = 1.f / R[i];
}

// ---------------- x_adp = [x, x1/R, x2/R] @ gcn_w + gcn_b   (in-place over x2) --------
__global__ __launch_bounds__(256) void k_gcn(const float* __restrict__ x,
                                             const float* __restrict__ x1,
                                             float* __restrict__ x2io,
                                             const float* __restrict__ Rinv,
                                             const float* __restrict__ gcn_w,
                                             const float* __restrict__ gcn_b) {
  __shared__ float W[96 * 32];
  __shared__ float bsh[32];
  __shared__ float rows[8][96];
  int tid = threadIdx.x;
  for (int i = tid; i < 96 * 32; i += 256) W[i] = gcn_w[i];
  if (tid < 32) bsh[tid] = gcn_b[tid];
  long base = (long)blockIdx.x * 8;
  int nloc = tid >> 5, c = tid & 31;
  long row = base + nloc;
  long nIdx = row % N_;
  float ri = Rinv[nIdx];
  rows[nloc][c] = x[row * 32 + c];
  rows[nloc][32 + c] = x1[row * 32 + c] * ri;
  rows[nloc][64 + c] = x2io[row * 32 + c] * ri;
  __syncthreads();
  float o = bsh[c];
#pragma unroll
  for (int k = 0; k < 96; k++) o = fmaf(rows[nloc][k], W[k * 32 + c], o);
  __syncthreads();
  x2io[row * 32 + c] = o;
}

// ---------------- collapsed slot attention + mean + elu (original, best measured) ------
__device__ __forceinline__ void load_row(int s, long r, const float* __restrict__ x,
                                         const __hip_bfloat16* __restrict__ hp16,
                                         const float* __restrict__ xadp, float* m) {
  if (s == 0 || s == 4) {
    const float4* p = (const float4*)((s == 0 ? x : xadp) + r * 32);
#pragma unroll
    for (int q = 0; q < 8; q++) {
      float4 v = p[q];
      m[q * 4 + 0] = v.x; m[q * 4 + 1] = v.y; m[q * 4 + 2] = v.z; m[q * 4 + 3] = v.w;
    }
  } else {
    const uint4* p = (const uint4*)(hp16 + ((long)(s - 1) * TN_ + r) * 32);
#pragma unroll
    for (int q = 0; q < 4; q++) {
      uint4 v = p[q];
      unsigned uu[4] = {v.x, v.y, v.z, v.w};
#pragma unroll
      for (int j = 0; j < 4; j++) {
        m[q * 8 + j * 2 + 0] = __uint_as_float(uu[j] << 16);
        m[q * 8 + j * 2 + 1] = __uint_as_float(uu[j] & 0xffff0000u);
      }
    }
  }
}

__global__ __launch_bounds__(256) void k_attn(const float* __restrict__ x,
                                              const __hip_bfloat16* __restrict__ hp16,
                                              const float* __restrict__ xadp,
                                              const float* __restrict__ prm,
                                              float* __restrict__ out) {
  __shared__ float Gs[1024], Hs[1024], g1s[32], g2s[32], hbs[32];
  __shared__ float g0sh;
  int tid = threadIdx.x;
  for (int i = tid; i < 1024; i += 256) { Gs[i] = prm[PRM_G + i]; Hs[i] = prm[PRM_H + i]; }
  if (tid < 32) { g1s[tid] = prm[PRM_G1 + tid]; g2s[tid] = prm[PRM_G2 + tid]; hbs[tid] = prm[PRM_HB + tid]; }
  if (tid == 0) g0sh = prm[PRM_G0];
  __syncthreads();
  long r = (long)blockIdx.x * 256 + tid;
  if (r >= TN_) return;
  float g0 = g0sh;
  float sc[5][5], d1[5], d2[5];
  float ms[32], mu[32], y[32];
#pragma unroll
  for (int s = 0; s < 5; s++) {
    load_row(s, r, x, hp16, xadp, ms);
    float a = 0.f, b = 0.f;
#pragma unroll
    for (int k = 0; k < 32; k++) { a = fmaf(ms[k], g1s[k], a); b = fmaf(ms[k], g2s[k], b); }
    d1[s] = a; d2[s] = b;
#pragma unroll
    for (int c = 0; c < 32; c++) {
      float s2 = 0.f;
#pragma unroll
      for (int k = 0; k < 32; k++) s2 = fmaf(ms[k], Gs[k * 32 + c], s2);
      y[c] = s2;
    }
#pragma unroll
    for (int u = 0; u < 5; u++) {
      load_row(u, r, x, hp16, xadp, mu);
      float dt = 0.f;
#pragma unroll
      for (int k = 0; k < 32; k++) dt = fmaf(y[k], mu[k], dt);
      sc[s][u] = dt;
    }
  }
  const float rs = 0.07216878364870322f;  // 1/sqrt(192)
  float abar[5];
#pragma unroll
  for (int u = 0; u < 5; u++) abar[u] = 0.f;
#pragma unroll
  for (int s = 0; s < 5; s++) {
    float e[5];
    float mx = -1e30f;
#pragma unroll
    for (int u = 0; u < 5; u++) {
      float v = (sc[s][u] + d1[s] + d2[u] + g0) * rs;
      e[u] = v;
      mx = fmaxf(mx, v);
    }
    float sm = 0.f;
#pragma unroll
    for (int u = 0; u < 5; u++) { e[u] = __expf(e[u] - mx); sm += e[u]; }
    float inv = 1.f / sm;
#pragma unroll
    for (int u = 0; u < 5; u++) abar[u] = fmaf(e[u], inv, abar[u]);
  }
  float z[32];
#pragma unroll
  for (int k = 0; k < 32; k++) z[k] = 0.f;
#pragma unroll
  for (int u = 0; u < 5; u++) {
    load_row(u, r, x, hp16, xadp, mu);
    float w = abar[u] * 0.2f;
#pragma unroll
    for (int k = 0; k < 32; k++) z[k] = fmaf(w, mu[k], z[k]);
  }
#pragma unroll
  for (int c = 0; c < 32; c++) {
    float o = hbs[c];
#pragma unroll
    for (int k = 0; k < 32; k++) o = fmaf(z[k], Hs[k * 32 + c], o);
    o = (o > 0.f) ? o : (__expf(o) - 1.f);
    out[r * 32 + c] = o;
  }
}

// ---------------- launch ----------------
extern "C" void kernel_launch(void* const* d_in, const int* in_sizes, int n_in,
                              void* d_out, int out_size, void* d_ws, size_t ws_size,
                              hipStream_t stream) {
  (void)in_sizes; (void)n_in; (void)out_size; (void)ws_size;
  const float* x          = (const float*)d_in[0];
  const float* timeoh     = (const float*)d_in[1];
  const int*   edges      = (const int*)d_in[2];
  const float* mlp_w      = (const float*)d_in[3];
  const float* mlp_b      = (const float*)d_in[4];
  const float* temb_w     = (const float*)d_in[5];
  const float* atten_pool = (const float*)d_in[6];
  const float* node2vec   = (const float*)d_in[7];
  const float* gcn_w      = (const float*)d_in[8];
  const float* gcn_b      = (const float*)d_in[9];
  const float* q_w  = (const float*)d_in[10];
  const float* q_b  = (const float*)d_in[11];
  const float* k_w  = (const float*)d_in[12];
  const float* k_b  = (const float*)d_in[13];
  const float* v_w  = (const float*)d_in[14];
  const float* v_b  = (const float*)d_in[15];
  const float* dense_w = (const float*)d_in[16];
  const float* dense_b = (const float*)d_in[17];
  float* out = (float*)d_out;
  char* ws = (char*)d_ws;

  float*    prm  = (float*)(ws + 0);
  float*    Mt   = (float*)(ws + 9216);
  int*      cnt  = (int*)(ws + 9472);
  int*      cur  = (int*)(ws + 129472);
  int*      offs = (int*)(ws + 249472);
  float*    ssrc = (float*)(ws + 369664);
  float*    sdst = (float*)(ws + 849664);
  float*    R    = (float*)(ws + 1329664);
  __hip_bfloat16* h16  = (__hip_bfloat16*)(ws + 1369664);
  int*      csr  = (int*)(ws + 9049664);
  __hip_bfloat16* hp16 = (__hip_bfloat16*)(ws + 12889664);
  float*    x1   = (float*)(ws + 35929664);
  float*    x2   = (float*)(ws + 51289664);
  short*    n2vA = (short*)(ws + 66649664);   //   640,000 B
  short*    xq0  = (short*)(ws + 67289664);   // 7,692,288 B
  short*    xq1  = (short*)(ws + 74983488);   // 7,692,288 B

  (void)hipMemsetAsync(cnt, 0, 120000, stream);
  (void)hipMemsetAsync(R, 0, 40000, stream);

  k_prep<<<1, 256, 0, stream>>>(timeoh, temb_w, atten_pool, q_w, q_b, k_w, k_b,
                                v_w, v_b, dense_w, dense_b, prm);
  k_h<<<15000, 256, 0, stream>>>(x, mlp_w, mlp_b, prm, h16, ssrc, sdst);
  k_maxs<<<12, 256, 0, stream>>>(ssrc, sdst, Mt);
  k_hist<<<dim3(1250, 3), 256, 0, stream>>>(edges, cnt);
  k_scan<<<3, 1024, 0, stream>>>(cnt, offs, cur);
  k_fill<<<dim3(1250, 3), 256, 0, stream>>>(edges, cur, csr);
  k_gather<<<dim3(2500, 12, 3), 256, 0, stream>>>(csr, offs, ssrc, sdst, Mt, h16, hp16);

  k_n2vA<<<157, 256, 0, stream>>>(node2vec, n2vA);
  k_pack<0><<<1878, 256, 0, stream>>>(x, nullptr, xq0);
  k_adj12<1><<<157, 512, 0, stream>>>(n2vA, xq0, x1, R);
  k_rinv<<<40, 256, 0, stream>>>(R);
  k_pack<1><<<1878, 256, 0, stream>>>(x1, R, xq1);
  k_adj12<2><<<157, 512, 0, stream>>>(n2vA, xq1, x2, nullptr);
  k_gcn<<<15000, 256, 0, stream>>>(x, x1, x2, R, gcn_w, gcn_b);
  k_attn<<<469, 256, 0, stream>>>(x, hp16, x2, prm, out);
}

// Round 23
// 804.827 us; speedup vs baseline: 1.2697x; 1.0477x over previous
//
#include <hip/hip_runtime.h>
#include <hip/hip_bf16.h>

#define T_ 12
#define N_ 10000
#define C_ 32
#define E_ 320000
#define SUP_ 3
#define TN_ (T_*N_)

typedef __attribute__((ext_vector_type(4))) float f32x4;
typedef __attribute__((ext_vector_type(8))) short bf16x8;
typedef __attribute__((ext_vector_type(4))) short bf16x4;

__device__ __forceinline__ short bf16c(float f) {
  __hip_bfloat16 b = __float2bfloat16(f);
  return (short)__builtin_bit_cast(unsigned short, b);
}

#if __has_builtin(__builtin_amdgcn_exp2f)
#define EXP2F(x) __builtin_amdgcn_exp2f(x)
#else
#define EXP2F(x) exp2f(x)
#endif

// prm layout (float offsets)
#define PRM_ATTN 0
#define PRM_G    64
#define PRM_H    1088
#define PRM_G1   2112
#define PRM_G2   2144
#define PRM_HB   2176
#define PRM_G0   2208

// ---------------- small precompute: attn vector + folded attention mats ----------------
__global__ __launch_bounds__(256) void k_prep(
    const float* __restrict__ timeoh, const float* __restrict__ temb_w,
    const float* __restrict__ atten_pool,
    const float* __restrict__ q_w, const float* __restrict__ q_b,
    const float* __restrict__ k_w, const float* __restrict__ k_b,
    const float* __restrict__ v_w, const float* __restrict__ v_b,
    const float* __restrict__ dense_w, const float* __restrict__ dense_b,
    float* __restrict__ prm) {
  __shared__ float tv[8];
  int tid = threadIdx.x;
  if (tid < 8) {
    float s = 0.f;
    for (int j = 0; j < 43; j++) s += timeoh[j] * temb_w[j * 8 + tid];
    tv[tid] = s;
  }
  __syncthreads();
  if (tid < 64) {
    float s = 0.f;
    for (int d = 0; d < 8; d++) s += tv[d] * atten_pool[d * 64 + tid];
    prm[PRM_ATTN + tid] = s;
  }
  for (int idx = tid; idx < 1024; idx += 256) {
    int r = idx >> 5, c = idx & 31;
    float s = 0.f, s2 = 0.f;
    for (int d = 0; d < 192; d++) {
      s  += q_w[r * 192 + d] * k_w[c * 192 + d];    // G = q_w @ k_w^T
      s2 += v_w[r * 192 + d] * dense_w[d * 32 + c]; // H = v_w @ dense_w
    }
    prm[PRM_G + idx] = s;
    prm[PRM_H + idx] = s2;
  }
  if (tid < 32) {
    float s = 0.f, s2 = 0.f, s3 = 0.f;
    for (int d = 0; d < 192; d++) {
      s  += q_w[tid * 192 + d] * k_b[d];
      s2 += k_w[tid * 192 + d] * q_b[d];
      s3 += v_b[d] * dense_w[d * 32 + tid];
    }
    prm[PRM_G1 + tid] = s;
    prm[PRM_G2 + tid] = s2;
    prm[PRM_HB + tid] = s3 + dense_b[tid];
  }
  if (tid == 0) {
    float s = 0.f;
    for (int d = 0; d < 192; d++) s += q_b[d] * k_b[d];
    prm[PRM_G0] = s;
  }
}

// ---------------- h = x@mlp_w+mlp_b (bf16, n-major [n][t][c]), s_src/s_dst [n][t] -------
__global__ __launch_bounds__(256) void k_h(
    const float* __restrict__ x, const float* __restrict__ mlp_w,
    const float* __restrict__ mlp_b, const float* __restrict__ prm,
    __hip_bfloat16* __restrict__ h16t, float* __restrict__ s_srct,
    float* __restrict__ s_dstt) {
  __shared__ float W[32 * 32];
  __shared__ float bsh[32], attnsh[64];
  __shared__ float xs[8][32];
  int tid = threadIdx.x;
  for (int i = tid; i < 1024; i += 256) W[i] = mlp_w[i];
  if (tid < 32) bsh[tid] = mlp_b[tid];
  if (tid < 64) attnsh[tid] = prm[PRM_ATTN + tid];
  long base = (long)blockIdx.x * 8;
  int nloc = tid >> 5, c = tid & 31;
  long row = base + nloc;  // flat t*N+n, grid sized exactly
  const int t = (int)(row / N_);
  const int n = (int)(row - (long)t * N_);
  xs[nloc][c] = x[row * 32 + c];
  __syncthreads();
  float hval = bsh[c];
#pragma unroll
  for (int k = 0; k < 32; k++) hval = fmaf(xs[nloc][k], W[k * 32 + c], hval);
  h16t[((long)n * 12 + t) * 32 + c] = __float2bfloat16(hval);
  float a = hval * attnsh[c], b = hval * attnsh[32 + c];
#pragma unroll
  for (int m = 16; m >= 1; m >>= 1) {
    a += __shfl_xor(a, m, 64);
    b += __shfl_xor(b, m, 64);
  }
  if (c == 0) { s_srct[(long)n * 12 + t] = a; s_dstt[(long)n * 12 + t] = b; }
}

// ---------------- per-t shift bound: M[t] = max_n ssrct + max_n sdstt -------------------
__global__ __launch_bounds__(256) void k_maxs(const float* __restrict__ ssrct,
                                              const float* __restrict__ sdstt,
                                              float* __restrict__ Mt) {
  __shared__ float sh[8];
  const int t = blockIdx.x, tid = threadIdx.x;
  float ma = -1e30f, mb = -1e30f;
  for (int i = tid; i < N_; i += 256) {
    ma = fmaxf(ma, ssrct[(long)i * 12 + t]);
    mb = fmaxf(mb, sdstt[(long)i * 12 + t]);
  }
#pragma unroll
  for (int k = 32; k >= 1; k >>= 1) {
    ma = fmaxf(ma, __shfl_xor(ma, k, 64));
    mb = fmaxf(mb, __shfl_xor(mb, k, 64));
  }
  if ((tid & 63) == 0) { sh[(tid >> 6) * 2] = ma; sh[(tid >> 6) * 2 + 1] = mb; }
  __syncthreads();
  if (tid == 0) {
    float A = fmaxf(fmaxf(sh[0], sh[2]), fmaxf(sh[4], sh[6]));
    float B = fmaxf(fmaxf(sh[1], sh[3]), fmaxf(sh[5], sh[7]));
    Mt[t] = A + B;
  }
}

// ---------------- CSR build ----------------
__global__ __launch_bounds__(256) void k_hist(const int* __restrict__ edges,
                                              int* __restrict__ cnt) {
  int sup = blockIdx.y;
  int e = blockIdx.x * 256 + threadIdx.x;
  const int* src = edges + (long)sup * 2 * E_;
  atomicAdd(&cnt[sup * N_ + src[e]], 1);
}

__global__ __launch_bounds__(1024) void k_scan(const int* __restrict__ cnt,
                                               int* __restrict__ offs,
                                               int* __restrict__ cur) {
  __shared__ int sh[1024];
  __shared__ int run;
  int sup = blockIdx.x, tid = threadIdx.x;
  if (tid == 0) run = 0;
  __syncthreads();
  for (int base = 0; base < N_; base += 1024) {
    int i = base + tid;
    int v = (i < N_) ? cnt[sup * N_ + i] : 0;
    sh[tid] = v;
    __syncthreads();
    for (int off = 1; off < 1024; off <<= 1) {
      int t = (tid >= off) ? sh[tid - off] : 0;
      __syncthreads();
      sh[tid] += t;
      __syncthreads();
    }
    int runv = run;
    int excl = runv + sh[tid] - v;
    if (i < N_) {
      offs[sup * (N_ + 1) + i] = excl;
      cur[sup * N_ + i] = excl;
    }
    __syncthreads();
    if (tid == 0) run = runv + sh[1023];
    __syncthreads();
  }
  if (tid == 0) offs[sup * (N_ + 1) + N_] = run;
}

__global__ __launch_bounds__(256) void k_fill(const int* __restrict__ edges,
                                              int* __restrict__ cur,
                                              int* __restrict__ csr) {
  int sup = blockIdx.y;
  int e = blockIdx.x * 256 + threadIdx.x;
  const int* src = edges + (long)sup * 2 * E_;
  const int* dst = src + E_;
  int pos = atomicAdd(&cur[sup * N_ + src[e]], 1);
  csr[sup * E_ + pos] = dst[e];
}

// ---------------- GAT gather v3: wave per (sup,n), ALL 12 t at once --------------------
// 48 active lanes = 12 t-groups x 4 lanes (16B of the 64B h row each). One edge per
// iteration (2-deep pipelined); serial accumulation -> NO shuffle reductions; csr/offs
// read once per n instead of 12x. h16t is n-major so the 12 t-rows of an edge's dst
// are one contiguous 768B read.
__global__ __launch_bounds__(256) void k_gather(
    const int* __restrict__ csr, const int* __restrict__ offs,
    const float* __restrict__ s_srct, const float* __restrict__ s_dstt,
    const float* __restrict__ Mt, const __hip_bfloat16* __restrict__ h16t,
    __hip_bfloat16* __restrict__ hp16) {
  const int sup = blockIdx.y;
  const int wave = threadIdx.x >> 6, lane = threadIdx.x & 63;
  const int n = blockIdx.x * 4 + wave;
  const int tg = (lane < 48) ? (lane >> 2) : 0;   // t group (lanes 48+ mirror tg=0)
  const int cl = lane & 3;                         // 16B slice of the row
  const float at = s_srct[(long)n * 12 + tg];
  const float Mv = Mt[tg];
  const int off = offs[sup * (N_ + 1) + n], end = offs[sup * (N_ + 1) + n + 1];
  const uint4* hb4 = (const uint4*)h16t;
  const int* csrs = csr + sup * E_;
  const int clamp = (end > off) ? (end - 1) : 0;

  float acc[8];
#pragma unroll
  for (int j = 0; j < 8; j++) acc[j] = 0.f;
  float psum = 0.f;

  int d0 = csrs[min(off, clamp)];
  int d1 = csrs[min(off + 1, clamp)];
  float sd0 = s_dstt[(long)d0 * 12 + tg];
  uint4 u0 = hb4[((long)d0 * 12 + tg) * 4 + cl];

  for (int idx = off; idx < end; idx++) {
    int d2 = csrs[min(idx + 2, clamp)];            // two ahead
    float sd1 = s_dstt[(long)d1 * 12 + tg];        // one ahead
    uint4 u1 = hb4[((long)d1 * 12 + tg) * 4 + cl];
    float v = at + sd0;
    v = fmaxf(v, 0.01f * v);                       // leaky
    float p = __expf(v - Mv);
    psum += p;
    acc[0] = fmaf(p, __uint_as_float(u0.x << 16),         acc[0]);
    acc[1] = fmaf(p, __uint_as_float(u0.x & 0xffff0000u), acc[1]);
    acc[2] = fmaf(p, __uint_as_float(u0.y << 16),         acc[2]);
    acc[3] = fmaf(p, __uint_as_float(u0.y & 0xffff0000u), acc[3]);
    acc[4] = fmaf(p, __uint_as_float(u0.z << 16),         acc[4]);
    acc[5] = fmaf(p, __uint_as_float(u0.z & 0xffff0000u), acc[5]);
    acc[6] = fmaf(p, __uint_as_float(u0.w << 16),         acc[6]);
    acc[7] = fmaf(p, __uint_as_float(u0.w & 0xffff0000u), acc[7]);
    d1 = d2; sd0 = sd1; u0 = u1;
  }

  if (lane < 48) {   // write-only epilogue: lane owns (t=tg, cols cl*8..cl*8+7)
    float inv = 1.f / (psum + 9e-15f);
    unsigned w[4];
#pragma unroll
    for (int q = 0; q < 4; q++) {
      float h0 = acc[2 * q + 0] * inv;
      float h1 = acc[2 * q + 1] * inv;
      h0 = (h0 > 0.f) ? h0 : (__expf(h0) - 1.f);
      h1 = (h1 > 0.f) ? h1 : (__expf(h1) - 1.f);
      unsigned lo = (unsigned)(unsigned short)__builtin_bit_cast(unsigned short, __float2bfloat16(h0));
      unsigned hi = (unsigned)(unsigned short)__builtin_bit_cast(unsigned short, __float2bfloat16(h1));
      w[q] = lo | (hi << 16);
    }
    ((uint4*)hp16)[((long)sup * TN_ + (long)tg * N_ + n) * 4 + cl] = uint4{w[0], w[1], w[2], w[3]};
  }
}

// ---------------- n2v -> bf16 frag-packed, PRE-SCALED by sqrt(log2 e) ------------------
__global__ __launch_bounds__(256) void k_n2vA(const float* __restrict__ n2v,
                                              short* __restrict__ n2vA) {
  const float SC = 1.2011224087864498f;  // sqrt(log2(e))
  int idx = blockIdx.x * 256 + threadIdx.x;
  if (idx >= N_ * 4) return;
  int row = idx >> 2, l4 = idx & 3;
  short v[8];
#pragma unroll
  for (int h = 0; h < 2; h++)
#pragma unroll
    for (int j = 0; j < 4; j++)
      v[h * 4 + j] = bf16c(n2v[row * 32 + 16 * h + 4 * l4 + j] * SC);
  *(bf16x8*)&n2vA[(long)idx * 8] = bf16x8{v[0], v[1], v[2], v[3], v[4], v[5], v[6], v[7]};
}

// ---------------- pack X (f32, optionally *rinv) into B-frag layout bf16 ---------------
template <int WITHR>
__global__ __launch_bounds__(256) void k_pack(const float* __restrict__ src,
                                              const float* __restrict__ rinv,
                                              short* __restrict__ xq) {
  int idx = blockIdx.x * 256 + threadIdx.x;  // 313*4*384 = 480768 exact
  int ck = idx / 1536;
  int rem = idx - ck * 1536;
  int l4 = rem / 384;
  int col = rem - l4 * 384;
  int t = col >> 5, f = col & 31;
  const long cb = (long)t * N_ * 32 + f;
  short v[8];
#pragma unroll
  for (int e = 0; e < 8; e++) {
    int vv = ck * 32 + 4 * l4 + (e & 3) + 16 * (e >> 2);
    float a = 0.f;
    if (vv < N_) {
      a = src[cb + (long)vv * 32];
      if (WITHR) a *= rinv[vv];
    }
    v[e] = bf16c(a);
  }
  *(bf16x8*)&xq[(long)idx * 8] = bf16x8{v[0], v[1], v[2], v[3], v[4], v[5], v[6], v[7]};
}

// ---------------- MFMA fused adj@X: LDS-shared aP, PING-PONG slabs, batched bx ---------
// (adj12 geometry — best measured: 175 us/pass.)
template <int PASS>
__global__ __launch_bounds__(512, 2) void k_adj12(const short* __restrict__ n2vA,
                                                  const short* __restrict__ xq,
                                                  float* __restrict__ out,
                                                  float* __restrict__ Rout) {
  __shared__ __align__(16) short aPl[2][8 * 4 * 64 * 8];  // 2 x 32 KB ping-pong
  const int tid = threadIdx.x;
  const int lane = tid & 63;
  const int wv = tid >> 6;       // 0..7 : colgroup in phase B, chunk-slot in phase A
  const int l15 = lane & 15;
  const int l4 = lane >> 4;      // 0..3
  const int brow0 = blockIdx.x * 64;
  const int colbase = wv * 48;

  bf16x8 bw[4];
#pragma unroll
  for (int mt = 0; mt < 4; mt++) {
    int row = brow0 + mt * 16 + l15;
    row = row < N_ ? row : N_ - 1;
    bw[mt] = *(const bf16x8*)&n2vA[((long)row * 4 + l4) * 8];
  }

  f32x4 acc[4][3];
#pragma unroll
  for (int i = 0; i < 4; i++)
#pragma unroll
    for (int j = 0; j < 3; j++) acc[i][j] = f32x4{0.f, 0.f, 0.f, 0.f};
  float racc[4] = {0.f, 0.f, 0.f, 0.f};

#define PHASE_A(cexpr, slab)                                                              \
  {                                                                                       \
    const int c_ = (cexpr);                                                               \
    if (c_ < 313) {                                                                       \
      const int vb_ = c_ * 32;                                                            \
      int r1_ = vb_ + 16 + l15; r1_ = r1_ < N_ ? r1_ : N_ - 1;                            \
      bf16x8 av0_ = *(const bf16x8*)&n2vA[((long)(vb_ + l15) * 4 + l4) * 8];              \
      bf16x8 av1_ = *(const bf16x8*)&n2vA[((long)r1_ * 4 + l4) * 8];                      \
      _Pragma("unroll")                                                                   \
      for (int mt = 0; mt < 4; mt++) {                                                    \
        f32x4 s0_ = __builtin_amdgcn_mfma_f32_16x16x32_bf16(av0_, bw[mt],                 \
                                                            f32x4{0.f,0.f,0.f,0.f},0,0,0);\
        f32x4 s1_ = __builtin_amdgcn_mfma_f32_16x16x32_bf16(av1_, bw[mt],                 \
                                                            f32x4{0.f,0.f,0.f,0.f},0,0,0);\
        short pp_[8];                                                                     \
        float rs0_ = 0.f, rs1_ = 0.f;                                                     \
        _Pragma("unroll")                                                                 \
        for (int j = 0; j < 4; j++) {                                                     \
          float p0_ = EXP2F(fmaxf(s0_[j], 0.f));                                          \
          float p1_ = EXP2F(fmaxf(s1_[j], 0.f));                                          \
          if constexpr (PASS == 1) { rs0_ += p0_; rs1_ += p1_; }                          \
          pp_[j] = bf16c(p0_);                                                            \
          pp_[j + 4] = bf16c(p1_);                                                        \
        }                                                                                 \
        *(bf16x8*)&aPl[slab][((wv * 4 + mt) * 64 + lane) * 8] =                           \
            bf16x8{pp_[0],pp_[1],pp_[2],pp_[3],pp_[4],pp_[5],pp_[6],pp_[7]};              \
        if constexpr (PASS == 1) racc[mt] += (c_ != 312) ? (rs0_ + rs1_) : rs0_;          \
      }                                                                                   \
    }                                                                                     \
  }

  PHASE_A(wv, 0)
  __syncthreads();

  for (int g = 0; g < 40; g++) {
    const int cur = g & 1;
    if (g + 1 < 40) PHASE_A((g + 1) * 8 + wv, cur ^ 1)

    const int rem = 313 - g * 8;
    if (rem >= 8) {
      bf16x8 bx[24];
#pragma unroll
      for (int cc = 0; cc < 8; cc++) {
        const long xb = (long)(g * 8 + cc) * 1536 + (long)l4 * 384;
        bx[cc * 3 + 0] = *(const bf16x8*)&xq[(xb + colbase + 0 * 16 + l15) * 8];
        bx[cc * 3 + 1] = *(const bf16x8*)&xq[(xb + colbase + 1 * 16 + l15) * 8];
        bx[cc * 3 + 2] = *(const bf16x8*)&xq[(xb + colbase + 2 * 16 + l15) * 8];
      }
#pragma unroll
      for (int cc = 0; cc < 8; cc++) {
#pragma unroll
        for (int mt = 0; mt < 4; mt++) {
          bf16x8 aP = *(const bf16x8*)&aPl[cur][((cc * 4 + mt) * 64 + lane) * 8];
          acc[mt][0] = __builtin_amdgcn_mfma_f32_16x16x32_bf16(aP, bx[cc * 3 + 0], acc[mt][0], 0, 0, 0);
          acc[mt][1] = __builtin_amdgcn_mfma_f32_16x16x32_bf16(aP, bx[cc * 3 + 1], acc[mt][1], 0, 0, 0);
          acc[mt][2] = __builtin_amdgcn_mfma_f32_16x16x32_bf16(aP, bx[cc * 3 + 2], acc[mt][2], 0, 0, 0);
        }
      }
    } else {
      for (int cc = 0; cc < rem; cc++) {
        const long xb = (long)(g * 8 + cc) * 1536 + (long)l4 * 384;
        bf16x8 bx0 = *(const bf16x8*)&xq[(xb + colbase + 0 * 16 + l15) * 8];
        bf16x8 bx1 = *(const bf16x8*)&xq[(xb + colbase + 1 * 16 + l15) * 8];
        bf16x8 bx2 = *(const bf16x8*)&xq[(xb + colbase + 2 * 16 + l15) * 8];
#pragma unroll
        for (int mt = 0; mt < 4; mt++) {
          bf16x8 aP = *(const bf16x8*)&aPl[cur][((cc * 4 + mt) * 64 + lane) * 8];
          acc[mt][0] = __builtin_amdgcn_mfma_f32_16x16x32_bf16(aP, bx0, acc[mt][0], 0, 0, 0);
          acc[mt][1] = __builtin_amdgcn_mfma_f32_16x16x32_bf16(aP, bx1, acc[mt][1], 0, 0, 0);
          acc[mt][2] = __builtin_amdgcn_mfma_f32_16x16x32_bf16(aP, bx2, acc[mt][2], 0, 0, 0);
        }
      }
    }
    __syncthreads();
  }
#undef PHASE_A

  if constexpr (PASS == 1) {
#pragma unroll
    for (int mt = 0; mt < 4; mt++) {
      float r = racc[mt];
      r += __shfl_xor(r, 16, 64);
      r += __shfl_xor(r, 32, 64);
      int w = brow0 + mt * 16 + l15;
      if (l4 == 0 && w < N_) atomicAdd(&Rout[w], r);
    }
  }
#pragma unroll
  for (int mt = 0; mt < 4; mt++) {
#pragma unroll
    for (int nt = 0; nt < 3; nt++) {
      const int col = colbase + nt * 16 + l15;
      const int t = col >> 5, f = col & 31;
#pragma unroll
      for (int j = 0; j < 4; j++) {
        const int w = brow0 + mt * 16 + 4 * l4 + j;
        if (w < N_) out[((long)t * N_ + w) * 32 + f] = acc[mt][nt][j];
      }
    }
  }
}

__global__ __launch_bounds__(256) void k_rinv(float* __restrict__ R) {
  int i = blockIdx.x * 256 + threadIdx.x;
  if (i < N_) R[i] = 1.f / R[i];
}

// ---------------- x_adp = [x, x1/R, x2/R] @ gcn_w + gcn_b   (in-place over x2) --------
__global__ __launch_bounds__(256) void k_gcn(const float* __restrict__ x,
                                             const float* __restrict__ x1,
                                             float* __restrict__ x2io,
                                             const float* __restrict__ Rinv,
                                             const float* __restrict__ gcn_w,
                                             const float* __restrict__ gcn_b) {
  __shared__ float W[96 * 32];
  __shared__ float bsh[32];
  __shared__ float rows[8][96];
  int tid = threadIdx.x;
  for (int i = tid; i < 96 * 32; i += 256) W[i] = gcn_w[i];
  if (tid < 32) bsh[tid] = gcn_b[tid];
  long base = (long)blockIdx.x * 8;
  int nloc = tid >> 5, c = tid & 31;
  long row = base + nloc;
  long nIdx = row % N_;
  float ri = Rinv[nIdx];
  rows[nloc][c] = x[row * 32 + c];
  rows[nloc][32 + c] = x1[row * 32 + c] * ri;
  rows[nloc][64 + c] = x2io[row * 32 + c] * ri;
  __syncthreads();
  float o = bsh[c];
#pragma unroll
  for (int k = 0; k < 96; k++) o = fmaf(rows[nloc][k], W[k * 32 + c], o);
  __syncthreads();
  x2io[row * 32 + c] = o;
}

// ---------------- collapsed slot attention + mean + elu (original, best measured) ------
__device__ __forceinline__ void load_row(int s, long r, const float* __restrict__ x,
                                         const __hip_bfloat16* __restrict__ hp16,
                                         const float* __restrict__ xadp, float* m) {
  if (s == 0 || s == 4) {
    const float4* p = (const float4*)((s == 0 ? x : xadp) + r * 32);
#pragma unroll
    for (int q = 0; q < 8; q++) {
      float4 v = p[q];
      m[q * 4 + 0] = v.x; m[q * 4 + 1] = v.y; m[q * 4 + 2] = v.z; m[q * 4 + 3] = v.w;
    }
  } else {
    const uint4* p = (const uint4*)(hp16 + ((long)(s - 1) * TN_ + r) * 32);
#pragma unroll
    for (int q = 0; q < 4; q++) {
      uint4 v = p[q];
      unsigned uu[4] = {v.x, v.y, v.z, v.w};
#pragma unroll
      for (int j = 0; j < 4; j++) {
        m[q * 8 + j * 2 + 0] = __uint_as_float(uu[j] << 16);
        m[q * 8 + j * 2 + 1] = __uint_as_float(uu[j] & 0xffff0000u);
      }
    }
  }
}

__global__ __launch_bounds__(256) void k_attn(const float* __restrict__ x,
                                              const __hip_bfloat16* __restrict__ hp16,
                                              const float* __restrict__ xadp,
                                              const float* __restrict__ prm,
                                              float* __restrict__ out) {
  __shared__ float Gs[1024], Hs[1024], g1s[32], g2s[32], hbs[32];
  __shared__ float g0sh;
  int tid = threadIdx.x;
  for (int i = tid; i < 1024; i += 256) { Gs[i] = prm[PRM_G + i]; Hs[i] = prm[PRM_H + i]; }
  if (tid < 32) { g1s[tid] = prm[PRM_G1 + tid]; g2s[tid] = prm[PRM_G2 + tid]; hbs[tid] = prm[PRM_HB + tid]; }
  if (tid == 0) g0sh = prm[PRM_G0];
  __syncthreads();
  long r = (long)blockIdx.x * 256 + tid;
  if (r >= TN_) return;
  float g0 = g0sh;
  float sc[5][5], d1[5], d2[5];
  float ms[32], mu[32], y[32];
#pragma unroll
  for (int s = 0; s < 5; s++) {
    load_row(s, r, x, hp16, xadp, ms);
    float a = 0.f, b = 0.f;
#pragma unroll
    for (int k = 0; k < 32; k++) { a = fmaf(ms[k], g1s[k], a); b = fmaf(ms[k], g2s[k], b); }
    d1[s] = a; d2[s] = b;
#pragma unroll
    for (int c = 0; c < 32; c++) {
      float s2 = 0.f;
#pragma unroll
      for (int k = 0; k < 32; k++) s2 = fmaf(ms[k], Gs[k * 32 + c], s2);
      y[c] = s2;
    }
#pragma unroll
    for (int u = 0; u < 5; u++) {
      load_row(u, r, x, hp16, xadp, mu);
      float dt = 0.f;
#pragma unroll
      for (int k = 0; k < 32; k++) dt = fmaf(y[k], mu[k], dt);
      sc[s][u] = dt;
    }
  }
  const float rs = 0.07216878364870322f;  // 1/sqrt(192)
  float abar[5];
#pragma unroll
  for (int u = 0; u < 5; u++) abar[u] = 0.f;
#pragma unroll
  for (int s = 0; s < 5; s++) {
    float e[5];
    float mx = -1e30f;
#pragma unroll
    for (int u = 0; u < 5; u++) {
      float v = (sc[s][u] + d1[s] + d2[u] + g0) * rs;
      e[u] = v;
      mx = fmaxf(mx, v);
    }
    float sm = 0.f;
#pragma unroll
    for (int u = 0; u < 5; u++) { e[u] = __expf(e[u] - mx); sm += e[u]; }
    float inv = 1.f / sm;
#pragma unroll
    for (int u = 0; u < 5; u++) abar[u] = fmaf(e[u], inv, abar[u]);
  }
  float z[32];
#pragma unroll
  for (int k = 0; k < 32; k++) z[k] = 0.f;
#pragma unroll
  for (int u = 0; u < 5; u++) {
    load_row(u, r, x, hp16, xadp, mu);
    float w = abar[u] * 0.2f;
#pragma unroll
    for (int k = 0; k < 32; k++) z[k] = fmaf(w, mu[k], z[k]);
  }
#pragma unroll
  for (int c = 0; c < 32; c++) {
    float o = hbs[c];
#pragma unroll
    for (int k = 0; k < 32; k++) o = fmaf(z[k], Hs[k * 32 + c], o);
    o = (o > 0.f) ? o : (__expf(o) - 1.f);
    out[r * 32 + c] = o;
  }
}

// ---------------- launch ----------------
extern "C" void kernel_launch(void* const* d_in, const int* in_sizes, int n_in,
                              void* d_out, int out_size, void* d_ws, size_t ws_size,
                              hipStream_t stream) {
  (void)in_sizes; (void)n_in; (void)out_size; (void)ws_size;
  const float* x          = (const float*)d_in[0];
  const float* timeoh     = (const float*)d_in[1];
  const int*   edges      = (const int*)d_in[2];
  const float* mlp_w      = (const float*)d_in[3];
  const float* mlp_b      = (const float*)d_in[4];
  const float* temb_w     = (const float*)d_in[5];
  const float* atten_pool = (const float*)d_in[6];
  const float* node2vec   = (const float*)d_in[7];
  const float* gcn_w      = (const float*)d_in[8];
  const float* gcn_b      = (const float*)d_in[9];
  const float* q_w  = (const float*)d_in[10];
  const float* q_b  = (const float*)d_in[11];
  const float* k_w  = (const float*)d_in[12];
  const float* k_b  = (const float*)d_in[13];
  const float* v_w  = (const float*)d_in[14];
  const float* v_b  = (const float*)d_in[15];
  const float* dense_w = (const float*)d_in[16];
  const float* dense_b = (const float*)d_in[17];
  float* out = (float*)d_out;
  char* ws = (char*)d_ws;

  float*    prm  = (float*)(ws + 0);
  float*    Mt   = (float*)(ws + 9216);
  int*      cnt  = (int*)(ws + 9472);
  int*      cur  = (int*)(ws + 129472);
  int*      offs = (int*)(ws + 249472);
  float*    ssrc = (float*)(ws + 369664);
  float*    sdst = (float*)(ws + 849664);
  float*    R    = (float*)(ws + 1329664);
  __hip_bfloat16* h16  = (__hip_bfloat16*)(ws + 1369664);
  int*      csr  = (int*)(ws + 9049664);
  __hip_bfloat16* hp16 = (__hip_bfloat16*)(ws + 12889664);
  float*    x1   = (float*)(ws + 35929664);
  float*    x2   = (float*)(ws + 51289664);
  short*    n2vA = (short*)(ws + 66649664);   //   640,000 B
  short*    xq0  = (short*)(ws + 67289664);   // 7,692,288 B
  short*    xq1  = (short*)(ws + 74983488);   // 7,692,288 B

  (void)hipMemsetAsync(cnt, 0, 120000, stream);
  (void)hipMemsetAsync(R, 0, 40000, stream);

  k_prep<<<1, 256, 0, stream>>>(timeoh, temb_w, atten_pool, q_w, q_b, k_w, k_b,
                                v_w, v_b, dense_w, dense_b, prm);
  k_h<<<15000, 256, 0, stream>>>(x, mlp_w, mlp_b, prm, h16, ssrc, sdst);
  k_maxs<<<12, 256, 0, stream>>>(ssrc, sdst, Mt);
  k_hist<<<dim3(1250, 3), 256, 0, stream>>>(edges, cnt);
  k_scan<<<3, 1024, 0, stream>>>(cnt, offs, cur);
  k_fill<<<dim3(1250, 3), 256, 0, stream>>>(edges, cur, csr);
  k_gather<<<dim3(2500, 3), 256, 0, stream>>>(csr, offs, ssrc, sdst, Mt, h16, hp16);

  k_n2vA<<<157, 256, 0, stream>>>(node2vec, n2vA);
  k_pack<0><<<1878, 256, 0, stream>>>(x, nullptr, xq0);
  k_adj12<1><<<157, 512, 0, stream>>>(n2vA, xq0, x1, R);
  k_rinv<<<40, 256, 0, stream>>>(R);
  k_pack<1><<<1878, 256, 0, stream>>>(x1, R, xq1);
  k_adj12<2><<<157, 512, 0, stream>>>(n2vA, xq1, x2, nullptr);
  k_gcn<<<15000, 256, 0, stream>>>(x, x1, x2, R, gcn_w, gcn_b);
  k_attn<<<469, 256, 0, stream>>>(x, hp16, x2, prm, out);
}

// Round 24
// 764.246 us; speedup vs baseline: 1.3371x; 1.0531x over previous
//
#include <hip/hip_runtime.h>
#include <hip/hip_bf16.h>

#define T_ 12
#define N_ 10000
#define C_ 32
#define E_ 320000
#define SUP_ 3
#define TN_ (T_*N_)

typedef __attribute__((ext_vector_type(4))) float f32x4;
typedef __attribute__((ext_vector_type(8))) short bf16x8;
typedef __attribute__((ext_vector_type(4))) short bf16x4;

__device__ __forceinline__ short bf16c(float f) {
  __hip_bfloat16 b = __float2bfloat16(f);
  return (short)__builtin_bit_cast(unsigned short, b);
}

#if __has_builtin(__builtin_amdgcn_exp2f)
#define EXP2F(x) __builtin_amdgcn_exp2f(x)
#else
#define EXP2F(x) exp2f(x)
#endif

// prm layout (float offsets)
#define PRM_ATTN 0
#define PRM_G    64
#define PRM_H    1088
#define PRM_G1   2112
#define PRM_G2   2144
#define PRM_HB   2176
#define PRM_G0   2208

// ---------------- small precompute: attn vector + folded attention mats ----------------
__global__ __launch_bounds__(256) void k_prep(
    const float* __restrict__ timeoh, const float* __restrict__ temb_w,
    const float* __restrict__ atten_pool,
    const float* __restrict__ q_w, const float* __restrict__ q_b,
    const float* __restrict__ k_w, const float* __restrict__ k_b,
    const float* __restrict__ v_w, const float* __restrict__ v_b,
    const float* __restrict__ dense_w, const float* __restrict__ dense_b,
    float* __restrict__ prm) {
  __shared__ float tv[8];
  int tid = threadIdx.x;
  if (tid < 8) {
    float s = 0.f;
    for (int j = 0; j < 43; j++) s += timeoh[j] * temb_w[j * 8 + tid];
    tv[tid] = s;
  }
  __syncthreads();
  if (tid < 64) {
    float s = 0.f;
    for (int d = 0; d < 8; d++) s += tv[d] * atten_pool[d * 64 + tid];
    prm[PRM_ATTN + tid] = s;
  }
  for (int idx = tid; idx < 1024; idx += 256) {
    int r = idx >> 5, c = idx & 31;
    float s = 0.f, s2 = 0.f;
    for (int d = 0; d < 192; d++) {
      s  += q_w[r * 192 + d] * k_w[c * 192 + d];    // G = q_w @ k_w^T
      s2 += v_w[r * 192 + d] * dense_w[d * 32 + c]; // H = v_w @ dense_w
    }
    prm[PRM_G + idx] = s;
    prm[PRM_H + idx] = s2;
  }
  if (tid < 32) {
    float s = 0.f, s2 = 0.f, s3 = 0.f;
    for (int d = 0; d < 192; d++) {
      s  += q_w[tid * 192 + d] * k_b[d];
      s2 += k_w[tid * 192 + d] * q_b[d];
      s3 += v_b[d] * dense_w[d * 32 + tid];
    }
    prm[PRM_G1 + tid] = s;
    prm[PRM_G2 + tid] = s2;
    prm[PRM_HB + tid] = s3 + dense_b[tid];
  }
  if (tid == 0) {
    float s = 0.f;
    for (int d = 0; d < 192; d++) s += q_b[d] * k_b[d];
    prm[PRM_G0] = s;
  }
}

// ---------------- h = x@mlp_w+mlp_b (bf16, n-major [n][t][c]), s_src/s_dst [n][t] -------
__global__ __launch_bounds__(256) void k_h(
    const float* __restrict__ x, const float* __restrict__ mlp_w,
    const float* __restrict__ mlp_b, const float* __restrict__ prm,
    __hip_bfloat16* __restrict__ h16t, float* __restrict__ s_srct,
    float* __restrict__ s_dstt) {
  __shared__ float W[32 * 32];
  __shared__ float bsh[32], attnsh[64];
  __shared__ float xs[8][32];
  int tid = threadIdx.x;
  for (int i = tid; i < 1024; i += 256) W[i] = mlp_w[i];
  if (tid < 32) bsh[tid] = mlp_b[tid];
  if (tid < 64) attnsh[tid] = prm[PRM_ATTN + tid];
  long base = (long)blockIdx.x * 8;
  int nloc = tid >> 5, c = tid & 31;
  long row = base + nloc;  // flat t*N+n, grid sized exactly
  const int t = (int)(row / N_);
  const int n = (int)(row - (long)t * N_);
  xs[nloc][c] = x[row * 32 + c];
  __syncthreads();
  float hval = bsh[c];
#pragma unroll
  for (int k = 0; k < 32; k++) hval = fmaf(xs[nloc][k], W[k * 32 + c], hval);
  h16t[((long)n * 12 + t) * 32 + c] = __float2bfloat16(hval);
  float a = hval * attnsh[c], b = hval * attnsh[32 + c];
#pragma unroll
  for (int m = 16; m >= 1; m >>= 1) {
    a += __shfl_xor(a, m, 64);
    b += __shfl_xor(b, m, 64);
  }
  if (c == 0) { s_srct[(long)n * 12 + t] = a; s_dstt[(long)n * 12 + t] = b; }
}

// ---------------- per-t shift bound: M[t] = max_n ssrct + max_n sdstt -------------------
__global__ __launch_bounds__(256) void k_maxs(const float* __restrict__ ssrct,
                                              const float* __restrict__ sdstt,
                                              float* __restrict__ Mt) {
  __shared__ float sh[8];
  const int t = blockIdx.x, tid = threadIdx.x;
  float ma = -1e30f, mb = -1e30f;
  for (int i = tid; i < N_; i += 256) {
    ma = fmaxf(ma, ssrct[(long)i * 12 + t]);
    mb = fmaxf(mb, sdstt[(long)i * 12 + t]);
  }
#pragma unroll
  for (int k = 32; k >= 1; k >>= 1) {
    ma = fmaxf(ma, __shfl_xor(ma, k, 64));
    mb = fmaxf(mb, __shfl_xor(mb, k, 64));
  }
  if ((tid & 63) == 0) { sh[(tid >> 6) * 2] = ma; sh[(tid >> 6) * 2 + 1] = mb; }
  __syncthreads();
  if (tid == 0) {
    float A = fmaxf(fmaxf(sh[0], sh[2]), fmaxf(sh[4], sh[6]));
    float B = fmaxf(fmaxf(sh[1], sh[3]), fmaxf(sh[5], sh[7]));
    Mt[t] = A + B;
  }
}

// ---------------- CSR build ----------------
__global__ __launch_bounds__(256) void k_hist(const int* __restrict__ edges,
                                              int* __restrict__ cnt) {
  int sup = blockIdx.y;
  int e = blockIdx.x * 256 + threadIdx.x;
  const int* src = edges + (long)sup * 2 * E_;
  atomicAdd(&cnt[sup * N_ + src[e]], 1);
}

__global__ __launch_bounds__(1024) void k_scan(const int* __restrict__ cnt,
                                               int* __restrict__ offs,
                                               int* __restrict__ cur) {
  __shared__ int sh[1024];
  __shared__ int run;
  int sup = blockIdx.x, tid = threadIdx.x;
  if (tid == 0) run = 0;
  __syncthreads();
  for (int base = 0; base < N_; base += 1024) {
    int i = base + tid;
    int v = (i < N_) ? cnt[sup * N_ + i] : 0;
    sh[tid] = v;
    __syncthreads();
    for (int off = 1; off < 1024; off <<= 1) {
      int t = (tid >= off) ? sh[tid - off] : 0;
      __syncthreads();
      sh[tid] += t;
      __syncthreads();
    }
    int runv = run;
    int excl = runv + sh[tid] - v;
    if (i < N_) {
      offs[sup * (N_ + 1) + i] = excl;
      cur[sup * N_ + i] = excl;
    }
    __syncthreads();
    if (tid == 0) run = runv + sh[1023];
    __syncthreads();
  }
  if (tid == 0) offs[sup * (N_ + 1) + N_] = run;
}

__global__ __launch_bounds__(256) void k_fill(const int* __restrict__ edges,
                                              int* __restrict__ cur,
                                              int* __restrict__ csr) {
  int sup = blockIdx.y;
  int e = blockIdx.x * 256 + threadIdx.x;
  const int* src = edges + (long)sup * 2 * E_;
  const int* dst = src + E_;
  int pos = atomicAdd(&cur[sup * N_ + src[e]], 1);
  csr[sup * E_ + pos] = dst[e];
}

// ---------------- GAT gather v3: wave per (sup,n), ALL 12 t at once --------------------
__global__ __launch_bounds__(256) void k_gather(
    const int* __restrict__ csr, const int* __restrict__ offs,
    const float* __restrict__ s_srct, const float* __restrict__ s_dstt,
    const float* __restrict__ Mt, const __hip_bfloat16* __restrict__ h16t,
    __hip_bfloat16* __restrict__ hp16) {
  const int sup = blockIdx.y;
  const int wave = threadIdx.x >> 6, lane = threadIdx.x & 63;
  const int n = blockIdx.x * 4 + wave;
  const int tg = (lane < 48) ? (lane >> 2) : 0;   // t group (lanes 48+ mirror tg=0)
  const int cl = lane & 3;                         // 16B slice of the row
  const float at = s_srct[(long)n * 12 + tg];
  const float Mv = Mt[tg];
  const int off = offs[sup * (N_ + 1) + n], end = offs[sup * (N_ + 1) + n + 1];
  const uint4* hb4 = (const uint4*)h16t;
  const int* csrs = csr + sup * E_;
  const int clamp = (end > off) ? (end - 1) : 0;

  float acc[8];
#pragma unroll
  for (int j = 0; j < 8; j++) acc[j] = 0.f;
  float psum = 0.f;

  int d0 = csrs[min(off, clamp)];
  int d1 = csrs[min(off + 1, clamp)];
  float sd0 = s_dstt[(long)d0 * 12 + tg];
  uint4 u0 = hb4[((long)d0 * 12 + tg) * 4 + cl];

  for (int idx = off; idx < end; idx++) {
    int d2 = csrs[min(idx + 2, clamp)];            // two ahead
    float sd1 = s_dstt[(long)d1 * 12 + tg];        // one ahead
    uint4 u1 = hb4[((long)d1 * 12 + tg) * 4 + cl];
    float v = at + sd0;
    v = fmaxf(v, 0.01f * v);                       // leaky
    float p = __expf(v - Mv);
    psum += p;
    acc[0] = fmaf(p, __uint_as_float(u0.x << 16),         acc[0]);
    acc[1] = fmaf(p, __uint_as_float(u0.x & 0xffff0000u), acc[1]);
    acc[2] = fmaf(p, __uint_as_float(u0.y << 16),         acc[2]);
    acc[3] = fmaf(p, __uint_as_float(u0.y & 0xffff0000u), acc[3]);
    acc[4] = fmaf(p, __uint_as_float(u0.z << 16),         acc[4]);
    acc[5] = fmaf(p, __uint_as_float(u0.z & 0xffff0000u), acc[5]);
    acc[6] = fmaf(p, __uint_as_float(u0.w << 16),         acc[6]);
    acc[7] = fmaf(p, __uint_as_float(u0.w & 0xffff0000u), acc[7]);
    d1 = d2; sd0 = sd1; u0 = u1;
  }

  if (lane < 48) {   // write-only epilogue: lane owns (t=tg, cols cl*8..cl*8+7)
    float inv = 1.f / (psum + 9e-15f);
    unsigned w[4];
#pragma unroll
    for (int q = 0; q < 4; q++) {
      float h0 = acc[2 * q + 0] * inv;
      float h1 = acc[2 * q + 1] * inv;
      h0 = (h0 > 0.f) ? h0 : (__expf(h0) - 1.f);
      h1 = (h1 > 0.f) ? h1 : (__expf(h1) - 1.f);
      unsigned lo = (unsigned)(unsigned short)__builtin_bit_cast(unsigned short, __float2bfloat16(h0));
      unsigned hi = (unsigned)(unsigned short)__builtin_bit_cast(unsigned short, __float2bfloat16(h1));
      w[q] = lo | (hi << 16);
    }
    ((uint4*)hp16)[((long)sup * TN_ + (long)tg * N_ + n) * 4 + cl] = uint4{w[0], w[1], w[2], w[3]};
  }
}

// ---------------- n2v -> bf16 frag-packed, PRE-SCALED by sqrt(log2 e) ------------------
__global__ __launch_bounds__(256) void k_n2vA(const float* __restrict__ n2v,
                                              short* __restrict__ n2vA) {
  const float SC = 1.2011224087864498f;  // sqrt(log2(e))
  int idx = blockIdx.x * 256 + threadIdx.x;
  if (idx >= N_ * 4) return;
  int row = idx >> 2, l4 = idx & 3;
  short v[8];
#pragma unroll
  for (int h = 0; h < 2; h++)
#pragma unroll
    for (int j = 0; j < 4; j++)
      v[h * 4 + j] = bf16c(n2v[row * 32 + 16 * h + 4 * l4 + j] * SC);
  *(bf16x8*)&n2vA[(long)idx * 8] = bf16x8{v[0], v[1], v[2], v[3], v[4], v[5], v[6], v[7]};
}

// ---------------- pack X (f32, optionally *rinv) into B-frag layout bf16 ---------------
template <int WITHR>
__global__ __launch_bounds__(256) void k_pack(const float* __restrict__ src,
                                              const float* __restrict__ rinv,
                                              short* __restrict__ xq) {
  int idx = blockIdx.x * 256 + threadIdx.x;  // 313*4*384 = 480768 exact
  int ck = idx / 1536;
  int rem = idx - ck * 1536;
  int l4 = rem / 384;
  int col = rem - l4 * 384;
  int t = col >> 5, f = col & 31;
  const long cb = (long)t * N_ * 32 + f;
  short v[8];
#pragma unroll
  for (int e = 0; e < 8; e++) {
    int vv = ck * 32 + 4 * l4 + (e & 3) + 16 * (e >> 2);
    float a = 0.f;
    if (vv < N_) {
      a = src[cb + (long)vv * 32];
      if (WITHR) a *= rinv[vv];
    }
    v[e] = bf16c(a);
  }
  *(bf16x8*)&xq[(long)idx * 8] = bf16x8{v[0], v[1], v[2], v[3], v[4], v[5], v[6], v[7]};
}

// ---------------- MFMA fused adj@X: LDS-shared aP, PING-PONG slabs, batched bx ---------
// (adj12 geometry, + T5 setprio around phase-B MFMA cluster: waves on a SIMD skew
// between phase A (exp/cvt-heavy) and phase B (MFMA-heavy) inside the barrier
// interval -> scheduler can favor the MFMA wave.)
template <int PASS>
__global__ __launch_bounds__(512, 2) void k_adj12(const short* __restrict__ n2vA,
                                                  const short* __restrict__ xq,
                                                  float* __restrict__ out,
                                                  float* __restrict__ Rout) {
  __shared__ __align__(16) short aPl[2][8 * 4 * 64 * 8];  // 2 x 32 KB ping-pong
  const int tid = threadIdx.x;
  const int lane = tid & 63;
  const int wv = tid >> 6;       // 0..7 : colgroup in phase B, chunk-slot in phase A
  const int l15 = lane & 15;
  const int l4 = lane >> 4;      // 0..3
  const int brow0 = blockIdx.x * 64;
  const int colbase = wv * 48;

  bf16x8 bw[4];
#pragma unroll
  for (int mt = 0; mt < 4; mt++) {
    int row = brow0 + mt * 16 + l15;
    row = row < N_ ? row : N_ - 1;
    bw[mt] = *(const bf16x8*)&n2vA[((long)row * 4 + l4) * 8];
  }

  f32x4 acc[4][3];
#pragma unroll
  for (int i = 0; i < 4; i++)
#pragma unroll
    for (int j = 0; j < 3; j++) acc[i][j] = f32x4{0.f, 0.f, 0.f, 0.f};
  float racc[4] = {0.f, 0.f, 0.f, 0.f};

#define PHASE_A(cexpr, slab)                                                              \
  {                                                                                       \
    const int c_ = (cexpr);                                                               \
    if (c_ < 313) {                                                                       \
      const int vb_ = c_ * 32;                                                            \
      int r1_ = vb_ + 16 + l15; r1_ = r1_ < N_ ? r1_ : N_ - 1;                            \
      bf16x8 av0_ = *(const bf16x8*)&n2vA[((long)(vb_ + l15) * 4 + l4) * 8];              \
      bf16x8 av1_ = *(const bf16x8*)&n2vA[((long)r1_ * 4 + l4) * 8];                      \
      _Pragma("unroll")                                                                   \
      for (int mt = 0; mt < 4; mt++) {                                                    \
        f32x4 s0_ = __builtin_amdgcn_mfma_f32_16x16x32_bf16(av0_, bw[mt],                 \
                                                            f32x4{0.f,0.f,0.f,0.f},0,0,0);\
        f32x4 s1_ = __builtin_amdgcn_mfma_f32_16x16x32_bf16(av1_, bw[mt],                 \
                                                            f32x4{0.f,0.f,0.f,0.f},0,0,0);\
        short pp_[8];                                                                     \
        float rs0_ = 0.f, rs1_ = 0.f;                                                     \
        _Pragma("unroll")                                                                 \
        for (int j = 0; j < 4; j++) {                                                     \
          float p0_ = EXP2F(fmaxf(s0_[j], 0.f));                                          \
          float p1_ = EXP2F(fmaxf(s1_[j], 0.f));                                          \
          if constexpr (PASS == 1) { rs0_ += p0_; rs1_ += p1_; }                          \
          pp_[j] = bf16c(p0_);                                                            \
          pp_[j + 4] = bf16c(p1_);                                                        \
        }                                                                                 \
        *(bf16x8*)&aPl[slab][((wv * 4 + mt) * 64 + lane) * 8] =                           \
            bf16x8{pp_[0],pp_[1],pp_[2],pp_[3],pp_[4],pp_[5],pp_[6],pp_[7]};              \
        if constexpr (PASS == 1) racc[mt] += (c_ != 312) ? (rs0_ + rs1_) : rs0_;          \
      }                                                                                   \
    }                                                                                     \
  }

  PHASE_A(wv, 0)
  __syncthreads();

  for (int g = 0; g < 40; g++) {
    const int cur = g & 1;
    if (g + 1 < 40) PHASE_A((g + 1) * 8 + wv, cur ^ 1)

    const int rem = 313 - g * 8;
    if (rem >= 8) {
      bf16x8 bx[24];
#pragma unroll
      for (int cc = 0; cc < 8; cc++) {
        const long xb = (long)(g * 8 + cc) * 1536 + (long)l4 * 384;
        bx[cc * 3 + 0] = *(const bf16x8*)&xq[(xb + colbase + 0 * 16 + l15) * 8];
        bx[cc * 3 + 1] = *(const bf16x8*)&xq[(xb + colbase + 1 * 16 + l15) * 8];
        bx[cc * 3 + 2] = *(const bf16x8*)&xq[(xb + colbase + 2 * 16 + l15) * 8];
      }
      __builtin_amdgcn_s_setprio(1);
#pragma unroll
      for (int cc = 0; cc < 8; cc++) {
#pragma unroll
        for (int mt = 0; mt < 4; mt++) {
          bf16x8 aP = *(const bf16x8*)&aPl[cur][((cc * 4 + mt) * 64 + lane) * 8];
          acc[mt][0] = __builtin_amdgcn_mfma_f32_16x16x32_bf16(aP, bx[cc * 3 + 0], acc[mt][0], 0, 0, 0);
          acc[mt][1] = __builtin_amdgcn_mfma_f32_16x16x32_bf16(aP, bx[cc * 3 + 1], acc[mt][1], 0, 0, 0);
          acc[mt][2] = __builtin_amdgcn_mfma_f32_16x16x32_bf16(aP, bx[cc * 3 + 2], acc[mt][2], 0, 0, 0);
        }
      }
      __builtin_amdgcn_s_setprio(0);
    } else {
      for (int cc = 0; cc < rem; cc++) {
        const long xb = (long)(g * 8 + cc) * 1536 + (long)l4 * 384;
        bf16x8 bx0 = *(const bf16x8*)&xq[(xb + colbase + 0 * 16 + l15) * 8];
        bf16x8 bx1 = *(const bf16x8*)&xq[(xb + colbase + 1 * 16 + l15) * 8];
        bf16x8 bx2 = *(const bf16x8*)&xq[(xb + colbase + 2 * 16 + l15) * 8];
#pragma unroll
        for (int mt = 0; mt < 4; mt++) {
          bf16x8 aP = *(const bf16x8*)&aPl[cur][((cc * 4 + mt) * 64 + lane) * 8];
          acc[mt][0] = __builtin_amdgcn_mfma_f32_16x16x32_bf16(aP, bx0, acc[mt][0], 0, 0, 0);
          acc[mt][1] = __builtin_amdgcn_mfma_f32_16x16x32_bf16(aP, bx1, acc[mt][1], 0, 0, 0);
          acc[mt][2] = __builtin_amdgcn_mfma_f32_16x16x32_bf16(aP, bx2, acc[mt][2], 0, 0, 0);
        }
      }
    }
    __syncthreads();
  }
#undef PHASE_A

  if constexpr (PASS == 1) {
#pragma unroll
    for (int mt = 0; mt < 4; mt++) {
      float r = racc[mt];
      r += __shfl_xor(r, 16, 64);
      r += __shfl_xor(r, 32, 64);
      int w = brow0 + mt * 16 + l15;
      if (l4 == 0 && w < N_) atomicAdd(&Rout[w], r);
    }
  }
#pragma unroll
  for (int mt = 0; mt < 4; mt++) {
#pragma unroll
    for (int nt = 0; nt < 3; nt++) {
      const int col = colbase + nt * 16 + l15;
      const int t = col >> 5, f = col & 31;
#pragma unroll
      for (int j = 0; j < 4; j++) {
        const int w = brow0 + mt * 16 + 4 * l4 + j;
        if (w < N_) out[((long)t * N_ + w) * 32 + f] = acc[mt][nt][j];
      }
    }
  }
}

__global__ __launch_bounds__(256) void k_rinv(float* __restrict__ R) {
  int i = blockIdx.x * 256 + threadIdx.x;
  if (i < N_) R[i] = 1.f / R[i];
}

// ---------------- x_adp = [x, x1/R, x2/R] @ gcn_w + gcn_b   (in-place over x2) --------
__global__ __launch_bounds__(256) void k_gcn(const float* __restrict__ x,
                                             const float* __restrict__ x1,
                                             float* __restrict__ x2io,
                                             const float* __restrict__ Rinv,
                                             const float* __restrict__ gcn_w,
                                             const float* __restrict__ gcn_b) {
  __shared__ float W[96 * 32];
  __shared__ float bsh[32];
  __shared__ float rows[8][96];
  int tid = threadIdx.x;
  for (int i = tid; i < 96 * 32; i += 256) W[i] = gcn_w[i];
  if (tid < 32) bsh[tid] = gcn_b[tid];
  long base = (long)blockIdx.x * 8;
  int nloc = tid >> 5, c = tid & 31;
  long row = base + nloc;
  long nIdx = row % N_;
  float ri = Rinv[nIdx];
  rows[nloc][c] = x[row * 32 + c];
  rows[nloc][32 + c] = x1[row * 32 + c] * ri;
  rows[nloc][64 + c] = x2io[row * 32 + c] * ri;
  __syncthreads();
  float o = bsh[c];
#pragma unroll
  for (int k = 0; k < 96; k++) o = fmaf(rows[nloc][k], W[k * 32 + c], o);
  __syncthreads();
  x2io[row * 32 + c] = o;
}

// ---------------- collapsed slot attention + mean + elu (original, best measured) ------
__device__ __forceinline__ void load_row(int s, long r, const float* __restrict__ x,
                                         const __hip_bfloat16* __restrict__ hp16,
                                         const float* __restrict__ xadp, float* m) {
  if (s == 0 || s == 4) {
    const float4* p = (const float4*)((s == 0 ? x : xadp) + r * 32);
#pragma unroll
    for (int q = 0; q < 8; q++) {
      float4 v = p[q];
      m[q * 4 + 0] = v.x; m[q * 4 + 1] = v.y; m[q * 4 + 2] = v.z; m[q * 4 + 3] = v.w;
    }
  } else {
    const uint4* p = (const uint4*)(hp16 + ((long)(s - 1) * TN_ + r) * 32);
#pragma unroll
    for (int q = 0; q < 4; q++) {
      uint4 v = p[q];
      unsigned uu[4] = {v.x, v.y, v.z, v.w};
#pragma unroll
      for (int j = 0; j < 4; j++) {
        m[q * 8 + j * 2 + 0] = __uint_as_float(uu[j] << 16);
        m[q * 8 + j * 2 + 1] = __uint_as_float(uu[j] & 0xffff0000u);
      }
    }
  }
}

__global__ __launch_bounds__(256) void k_attn(const float* __restrict__ x,
                                              const __hip_bfloat16* __restrict__ hp16,
                                              const float* __restrict__ xadp,
                                              const float* __restrict__ prm,
                                              float* __restrict__ out) {
  __shared__ float Gs[1024], Hs[1024], g1s[32], g2s[32], hbs[32];
  __shared__ float g0sh;
  int tid = threadIdx.x;
  for (int i = tid; i < 1024; i += 256) { Gs[i] = prm[PRM_G + i]; Hs[i] = prm[PRM_H + i]; }
  if (tid < 32) { g1s[tid] = prm[PRM_G1 + tid]; g2s[tid] = prm[PRM_G2 + tid]; hbs[tid] = prm[PRM_HB + tid]; }
  if (tid == 0) g0sh = prm[PRM_G0];
  __syncthreads();
  long r = (long)blockIdx.x * 256 + tid;
  if (r >= TN_) return;
  float g0 = g0sh;
  float sc[5][5], d1[5], d2[5];
  float ms[32], mu[32], y[32];
#pragma unroll
  for (int s = 0; s < 5; s++) {
    load_row(s, r, x, hp16, xadp, ms);
    float a = 0.f, b = 0.f;
#pragma unroll
    for (int k = 0; k < 32; k++) { a = fmaf(ms[k], g1s[k], a); b = fmaf(ms[k], g2s[k], b); }
    d1[s] = a; d2[s] = b;
#pragma unroll
    for (int c = 0; c < 32; c++) {
      float s2 = 0.f;
#pragma unroll
      for (int k = 0; k < 32; k++) s2 = fmaf(ms[k], Gs[k * 32 + c], s2);
      y[c] = s2;
    }
#pragma unroll
    for (int u = 0; u < 5; u++) {
      load_row(u, r, x, hp16, xadp, mu);
      float dt = 0.f;
#pragma unroll
      for (int k = 0; k < 32; k++) dt = fmaf(y[k], mu[k], dt);
      sc[s][u] = dt;
    }
  }
  const float rs = 0.07216878364870322f;  // 1/sqrt(192)
  float abar[5];
#pragma unroll
  for (int u = 0; u < 5; u++) abar[u] = 0.f;
#pragma unroll
  for (int s = 0; s < 5; s++) {
    float e[5];
    float mx = -1e30f;
#pragma unroll
    for (int u = 0; u < 5; u++) {
      float v = (sc[s][u] + d1[s] + d2[u] + g0) * rs;
      e[u] = v;
      mx = fmaxf(mx, v);
    }
    float sm = 0.f;
#pragma unroll
    for (int u = 0; u < 5; u++) { e[u] = __expf(e[u] - mx); sm += e[u]; }
    float inv = 1.f / sm;
#pragma unroll
    for (int u = 0; u < 5; u++) abar[u] = fmaf(e[u], inv, abar[u]);
  }
  float z[32];
#pragma unroll
  for (int k = 0; k < 32; k++) z[k] = 0.f;
#pragma unroll
  for (int u = 0; u < 5; u++) {
    load_row(u, r, x, hp16, xadp, mu);
    float w = abar[u] * 0.2f;
#pragma unroll
    for (int k = 0; k < 32; k++) z[k] = fmaf(w, mu[k], z[k]);
  }
#pragma unroll
  for (int c = 0; c < 32; c++) {
    float o = hbs[c];
#pragma unroll
    for (int k = 0; k < 32; k++) o = fmaf(z[k], Hs[k * 32 + c], o);
    o = (o > 0.f) ? o : (__expf(o) - 1.f);
    out[r * 32 + c] = o;
  }
}

// ---------------- launch ----------------
extern "C" void kernel_launch(void* const* d_in, const int* in_sizes, int n_in,
                              void* d_out, int out_size, void* d_ws, size_t ws_size,
                              hipStream_t stream) {
  (void)in_sizes; (void)n_in; (void)out_size; (void)ws_size;
  const float* x          = (const float*)d_in[0];
  const float* timeoh     = (const float*)d_in[1];
  const int*   edges      = (const int*)d_in[2];
  const float* mlp_w      = (const float*)d_in[3];
  const float* mlp_b      = (const float*)d_in[4];
  const float* temb_w     = (const float*)d_in[5];
  const float* atten_pool = (const float*)d_in[6];
  const float* node2vec   = (const float*)d_in[7];
  const float* gcn_w      = (const float*)d_in[8];
  const float* gcn_b      = (const float*)d_in[9];
  const float* q_w  = (const float*)d_in[10];
  const float* q_b  = (const float*)d_in[11];
  const float* k_w  = (const float*)d_in[12];
  const float* k_b  = (const float*)d_in[13];
  const float* v_w  = (const float*)d_in[14];
  const float* v_b  = (const float*)d_in[15];
  const float* dense_w = (const float*)d_in[16];
  const float* dense_b = (const float*)d_in[17];
  float* out = (float*)d_out;
  char* ws = (char*)d_ws;

  float*    prm  = (float*)(ws + 0);
  float*    Mt   = (float*)(ws + 9216);
  int*      cnt  = (int*)(ws + 9472);
  int*      cur  = (int*)(ws + 129472);
  int*      offs = (int*)(ws + 249472);
  float*    ssrc = (float*)(ws + 369664);
  float*    sdst = (float*)(ws + 849664);
  float*    R    = (float*)(ws + 1329664);
  __hip_bfloat16* h16  = (__hip_bfloat16*)(ws + 1369664);
  int*      csr  = (int*)(ws + 9049664);
  __hip_bfloat16* hp16 = (__hip_bfloat16*)(ws + 12889664);
  float*    x1   = (float*)(ws + 35929664);
  float*    x2   = (float*)(ws + 51289664);
  short*    n2vA = (short*)(ws + 66649664);   //   640,000 B
  short*    xq0  = (short*)(ws + 67289664);   // 7,692,288 B
  short*    xq1  = (short*)(ws + 74983488);   // 7,692,288 B

  (void)hipMemsetAsync(cnt, 0, 120000, stream);
  (void)hipMemsetAsync(R, 0, 40000, stream);

  k_prep<<<1, 256, 0, stream>>>(timeoh, temb_w, atten_pool, q_w, q_b, k_w, k_b,
                                v_w, v_b, dense_w, dense_b, prm);
  k_h<<<15000, 256, 0, stream>>>(x, mlp_w, mlp_b, prm, h16, ssrc, sdst);
  k_maxs<<<12, 256, 0, stream>>>(ssrc, sdst, Mt);
  k_hist<<<dim3(1250, 3), 256, 0, stream>>>(edges, cnt);
  k_scan<<<3, 1024, 0, stream>>>(cnt, offs, cur);
  k_fill<<<dim3(1250, 3), 256, 0, stream>>>(edges, cur, csr);
  k_gather<<<dim3(2500, 3), 256, 0, stream>>>(csr, offs, ssrc, sdst, Mt, h16, hp16);

  k_n2vA<<<157, 256, 0, stream>>>(node2vec, n2vA);
  k_pack<0><<<1878, 256, 0, stream>>>(x, nullptr, xq0);
  k_adj12<1><<<157, 512, 0, stream>>>(n2vA, xq0, x1, R);
  k_rinv<<<40, 256, 0, stream>>>(R);
  k_pack<1><<<1878, 256, 0, stream>>>(x1, R, xq1);
  k_adj12<2><<<157, 512, 0, stream>>>(n2vA, xq1, x2, nullptr);
  k_gcn<<<15000, 256, 0, stream>>>(x, x1, x2, R, gcn_w, gcn_b);
  k_attn<<<469, 256, 0, stream>>>(x, hp16, x2, prm, out);
}

// Round 25
// 759.140 us; speedup vs baseline: 1.3461x; 1.0067x over previous
//
#include <hip/hip_runtime.h>
#include <hip/hip_bf16.h>

#define T_ 12
#define N_ 10000
#define C_ 32
#define E_ 320000
#define SUP_ 3
#define TN_ (T_*N_)

typedef __attribute__((ext_vector_type(4))) float f32x4;
typedef __attribute__((ext_vector_type(8))) short bf16x8;
typedef __attribute__((ext_vector_type(4))) short bf16x4;

__device__ __forceinline__ short bf16c(float f) {
  __hip_bfloat16 b = __float2bfloat16(f);
  return (short)__builtin_bit_cast(unsigned short, b);
}

#if __has_builtin(__builtin_amdgcn_exp2f)
#define EXP2F(x) __builtin_amdgcn_exp2f(x)
#else
#define EXP2F(x) exp2f(x)
#endif

// prm layout (float offsets)
#define PRM_ATTN 0
#define PRM_G    64
#define PRM_H    1088
#define PRM_G1   2112
#define PRM_G2   2144
#define PRM_HB   2176
#define PRM_G0   2208

// ---------------- small precompute: attn vector + folded attention mats ----------------
__global__ __launch_bounds__(256) void k_prep(
    const float* __restrict__ timeoh, const float* __restrict__ temb_w,
    const float* __restrict__ atten_pool,
    const float* __restrict__ q_w, const float* __restrict__ q_b,
    const float* __restrict__ k_w, const float* __restrict__ k_b,
    const float* __restrict__ v_w, const float* __restrict__ v_b,
    const float* __restrict__ dense_w, const float* __restrict__ dense_b,
    float* __restrict__ prm) {
  __shared__ float tv[8];
  int tid = threadIdx.x;
  if (tid < 8) {
    float s = 0.f;
    for (int j = 0; j < 43; j++) s += timeoh[j] * temb_w[j * 8 + tid];
    tv[tid] = s;
  }
  __syncthreads();
  if (tid < 64) {
    float s = 0.f;
    for (int d = 0; d < 8; d++) s += tv[d] * atten_pool[d * 64 + tid];
    prm[PRM_ATTN + tid] = s;
  }
  for (int idx = tid; idx < 1024; idx += 256) {
    int r = idx >> 5, c = idx & 31;
    float s = 0.f, s2 = 0.f;
    for (int d = 0; d < 192; d++) {
      s  += q_w[r * 192 + d] * k_w[c * 192 + d];    // G = q_w @ k_w^T
      s2 += v_w[r * 192 + d] * dense_w[d * 32 + c]; // H = v_w @ dense_w
    }
    prm[PRM_G + idx] = s;
    prm[PRM_H + idx] = s2;
  }
  if (tid < 32) {
    float s = 0.f, s2 = 0.f, s3 = 0.f;
    for (int d = 0; d < 192; d++) {
      s  += q_w[tid * 192 + d] * k_b[d];
      s2 += k_w[tid * 192 + d] * q_b[d];
      s3 += v_b[d] * dense_w[d * 32 + tid];
    }
    prm[PRM_G1 + tid] = s;
    prm[PRM_G2 + tid] = s2;
    prm[PRM_HB + tid] = s3 + dense_b[tid];
  }
  if (tid == 0) {
    float s = 0.f;
    for (int d = 0; d < 192; d++) s += q_b[d] * k_b[d];
    prm[PRM_G0] = s;
  }
}

// ---------------- h = x@mlp_w+mlp_b (bf16, n-major [n][t][c]), s_src/s_dst [n][t] -------
__global__ __launch_bounds__(256) void k_h(
    const float* __restrict__ x, const float* __restrict__ mlp_w,
    const float* __restrict__ mlp_b, const float* __restrict__ prm,
    __hip_bfloat16* __restrict__ h16t, float* __restrict__ s_srct,
    float* __restrict__ s_dstt) {
  __shared__ float W[32 * 32];
  __shared__ float bsh[32], attnsh[64];
  __shared__ float xs[8][32];
  int tid = threadIdx.x;
  for (int i = tid; i < 1024; i += 256) W[i] = mlp_w[i];
  if (tid < 32) bsh[tid] = mlp_b[tid];
  if (tid < 64) attnsh[tid] = prm[PRM_ATTN + tid];
  long base = (long)blockIdx.x * 8;
  int nloc = tid >> 5, c = tid & 31;
  long row = base + nloc;  // flat t*N+n, grid sized exactly
  const int t = (int)(row / N_);
  const int n = (int)(row - (long)t * N_);
  xs[nloc][c] = x[row * 32 + c];
  __syncthreads();
  float hval = bsh[c];
#pragma unroll
  for (int k = 0; k < 32; k++) hval = fmaf(xs[nloc][k], W[k * 32 + c], hval);
  h16t[((long)n * 12 + t) * 32 + c] = __float2bfloat16(hval);
  float a = hval * attnsh[c], b = hval * attnsh[32 + c];
#pragma unroll
  for (int m = 16; m >= 1; m >>= 1) {
    a += __shfl_xor(a, m, 64);
    b += __shfl_xor(b, m, 64);
  }
  if (c == 0) { s_srct[(long)n * 12 + t] = a; s_dstt[(long)n * 12 + t] = b; }
}

// ---------------- per-t shift bound: M[t] = max_n ssrct + max_n sdstt -------------------
__global__ __launch_bounds__(256) void k_maxs(const float* __restrict__ ssrct,
                                              const float* __restrict__ sdstt,
                                              float* __restrict__ Mt) {
  __shared__ float sh[8];
  const int t = blockIdx.x, tid = threadIdx.x;
  float ma = -1e30f, mb = -1e30f;
  for (int i = tid; i < N_; i += 256) {
    ma = fmaxf(ma, ssrct[(long)i * 12 + t]);
    mb = fmaxf(mb, sdstt[(long)i * 12 + t]);
  }
#pragma unroll
  for (int k = 32; k >= 1; k >>= 1) {
    ma = fmaxf(ma, __shfl_xor(ma, k, 64));
    mb = fmaxf(mb, __shfl_xor(mb, k, 64));
  }
  if ((tid & 63) == 0) { sh[(tid >> 6) * 2] = ma; sh[(tid >> 6) * 2 + 1] = mb; }
  __syncthreads();
  if (tid == 0) {
    float A = fmaxf(fmaxf(sh[0], sh[2]), fmaxf(sh[4], sh[6]));
    float B = fmaxf(fmaxf(sh[1], sh[3]), fmaxf(sh[5], sh[7]));
    Mt[t] = A + B;
  }
}

// ---------------- CSR build ----------------
__global__ __launch_bounds__(256) void k_hist(const int* __restrict__ edges,
                                              int* __restrict__ cnt) {
  int sup = blockIdx.y;
  int e = blockIdx.x * 256 + threadIdx.x;
  const int* src = edges + (long)sup * 2 * E_;
  atomicAdd(&cnt[sup * N_ + src[e]], 1);
}

__global__ __launch_bounds__(1024) void k_scan(const int* __restrict__ cnt,
                                               int* __restrict__ offs,
                                               int* __restrict__ cur) {
  __shared__ int sh[1024];
  __shared__ int run;
  int sup = blockIdx.x, tid = threadIdx.x;
  if (tid == 0) run = 0;
  __syncthreads();
  for (int base = 0; base < N_; base += 1024) {
    int i = base + tid;
    int v = (i < N_) ? cnt[sup * N_ + i] : 0;
    sh[tid] = v;
    __syncthreads();
    for (int off = 1; off < 1024; off <<= 1) {
      int t = (tid >= off) ? sh[tid - off] : 0;
      __syncthreads();
      sh[tid] += t;
      __syncthreads();
    }
    int runv = run;
    int excl = runv + sh[tid] - v;
    if (i < N_) {
      offs[sup * (N_ + 1) + i] = excl;
      cur[sup * N_ + i] = excl;
    }
    __syncthreads();
    if (tid == 0) run = runv + sh[1023];
    __syncthreads();
  }
  if (tid == 0) offs[sup * (N_ + 1) + N_] = run;
}

__global__ __launch_bounds__(256) void k_fill(const int* __restrict__ edges,
                                              int* __restrict__ cur,
                                              int* __restrict__ csr) {
  int sup = blockIdx.y;
  int e = blockIdx.x * 256 + threadIdx.x;
  const int* src = edges + (long)sup * 2 * E_;
  const int* dst = src + E_;
  int pos = atomicAdd(&cur[sup * N_ + src[e]], 1);
  csr[sup * E_ + pos] = dst[e];
}

// ---------------- GAT gather v3: wave per (sup,n), ALL 12 t at once --------------------
__global__ __launch_bounds__(256) void k_gather(
    const int* __restrict__ csr, const int* __restrict__ offs,
    const float* __restrict__ s_srct, const float* __restrict__ s_dstt,
    const float* __restrict__ Mt, const __hip_bfloat16* __restrict__ h16t,
    __hip_bfloat16* __restrict__ hp16) {
  const int sup = blockIdx.y;
  const int wave = threadIdx.x >> 6, lane = threadIdx.x & 63;
  const int n = blockIdx.x * 4 + wave;
  const int tg = (lane < 48) ? (lane >> 2) : 0;   // t group (lanes 48+ mirror tg=0)
  const int cl = lane & 3;                         // 16B slice of the row
  const float at = s_srct[(long)n * 12 + tg];
  const float Mv = Mt[tg];
  const int off = offs[sup * (N_ + 1) + n], end = offs[sup * (N_ + 1) + n + 1];
  const uint4* hb4 = (const uint4*)h16t;
  const int* csrs = csr + sup * E_;
  const int clamp = (end > off) ? (end - 1) : 0;

  float acc[8];
#pragma unroll
  for (int j = 0; j < 8; j++) acc[j] = 0.f;
  float psum = 0.f;

  int d0 = csrs[min(off, clamp)];
  int d1 = csrs[min(off + 1, clamp)];
  float sd0 = s_dstt[(long)d0 * 12 + tg];
  uint4 u0 = hb4[((long)d0 * 12 + tg) * 4 + cl];

  for (int idx = off; idx < end; idx++) {
    int d2 = csrs[min(idx + 2, clamp)];            // two ahead
    float sd1 = s_dstt[(long)d1 * 12 + tg];        // one ahead
    uint4 u1 = hb4[((long)d1 * 12 + tg) * 4 + cl];
    float v = at + sd0;
    v = fmaxf(v, 0.01f * v);                       // leaky
    float p = __expf(v - Mv);
    psum += p;
    acc[0] = fmaf(p, __uint_as_float(u0.x << 16),         acc[0]);
    acc[1] = fmaf(p, __uint_as_float(u0.x & 0xffff0000u), acc[1]);
    acc[2] = fmaf(p, __uint_as_float(u0.y << 16),         acc[2]);
    acc[3] = fmaf(p, __uint_as_float(u0.y & 0xffff0000u), acc[3]);
    acc[4] = fmaf(p, __uint_as_float(u0.z << 16),         acc[4]);
    acc[5] = fmaf(p, __uint_as_float(u0.z & 0xffff0000u), acc[5]);
    acc[6] = fmaf(p, __uint_as_float(u0.w << 16),         acc[6]);
    acc[7] = fmaf(p, __uint_as_float(u0.w & 0xffff0000u), acc[7]);
    d1 = d2; sd0 = sd1; u0 = u1;
  }

  if (lane < 48) {   // write-only epilogue: lane owns (t=tg, cols cl*8..cl*8+7)
    float inv = 1.f / (psum + 9e-15f);
    unsigned w[4];
#pragma unroll
    for (int q = 0; q < 4; q++) {
      float h0 = acc[2 * q + 0] * inv;
      float h1 = acc[2 * q + 1] * inv;
      h0 = (h0 > 0.f) ? h0 : (__expf(h0) - 1.f);
      h1 = (h1 > 0.f) ? h1 : (__expf(h1) - 1.f);
      unsigned lo = (unsigned)(unsigned short)__builtin_bit_cast(unsigned short, __float2bfloat16(h0));
      unsigned hi = (unsigned)(unsigned short)__builtin_bit_cast(unsigned short, __float2bfloat16(h1));
      w[q] = lo | (hi << 16);
    }
    ((uint4*)hp16)[((long)sup * TN_ + (long)tg * N_ + n) * 4 + cl] = uint4{w[0], w[1], w[2], w[3]};
  }
}

// ---------------- n2v -> bf16 frag-packed, PRE-SCALED by sqrt(log2 e) ------------------
__global__ __launch_bounds__(256) void k_n2vA(const float* __restrict__ n2v,
                                              short* __restrict__ n2vA) {
  const float SC = 1.2011224087864498f;  // sqrt(log2(e))
  int idx = blockIdx.x * 256 + threadIdx.x;
  if (idx >= N_ * 4) return;
  int row = idx >> 2, l4 = idx & 3;
  short v[8];
#pragma unroll
  for (int h = 0; h < 2; h++)
#pragma unroll
    for (int j = 0; j < 4; j++)
      v[h * 4 + j] = bf16c(n2v[row * 32 + 16 * h + 4 * l4 + j] * SC);
  *(bf16x8*)&n2vA[(long)idx * 8] = bf16x8{v[0], v[1], v[2], v[3], v[4], v[5], v[6], v[7]};
}

// ---------------- pack X f32 -> B-frag layout bf16 (pass-0 only; pass-1 fused) ---------
__global__ __launch_bounds__(256) void k_pack0(const float* __restrict__ src,
                                               short* __restrict__ xq) {
  int idx = blockIdx.x * 256 + threadIdx.x;  // 313*4*384 = 480768 exact
  int ck = idx / 1536;
  int rem = idx - ck * 1536;
  int l4 = rem / 384;
  int col = rem - l4 * 384;
  int t = col >> 5, f = col & 31;
  const long cb = (long)t * N_ * 32 + f;
  short v[8];
#pragma unroll
  for (int e = 0; e < 8; e++) {
    int vv = ck * 32 + 4 * l4 + (e & 3) + 16 * (e >> 2);
    float a = 0.f;
    if (vv < N_) a = src[cb + (long)vv * 32];
    v[e] = bf16c(a);
  }
  *(bf16x8*)&xq[(long)idx * 8] = bf16x8{v[0], v[1], v[2], v[3], v[4], v[5], v[6], v[7]};
}

// ---------------- MFMA fused adj@X: LDS-shared aP, ping-pong, batched bx, T5 setprio ---
// PASS 1 extra fusion: R is block-local (block covers all 313 chunks for its 64 rows) ->
// LDS-reduce R across waves, write rinv directly to Rout (kills k_rinv), and pack xq1
// bf16 straight from accumulator registers (kills k_pack<1>): each thread holds exactly
// the 8 row-values one bf16x8 xq entry needs (mt pairs x j) at its col.
template <int PASS>
__global__ __launch_bounds__(512, 2) void k_adj12(const short* __restrict__ n2vA,
                                                  const short* __restrict__ xq,
                                                  float* __restrict__ out,
                                                  float* __restrict__ Rout,
                                                  short* __restrict__ xqout) {
  __shared__ __align__(16) short aPl[2][8 * 4 * 64 * 8];  // 2 x 32 KB ping-pong
  const int tid = threadIdx.x;
  const int lane = tid & 63;
  const int wv = tid >> 6;       // 0..7 : colgroup in phase B, chunk-slot in phase A
  const int l15 = lane & 15;
  const int l4 = lane >> 4;      // 0..3
  const int brow0 = blockIdx.x * 64;
  const int colbase = wv * 48;

  bf16x8 bw[4];
#pragma unroll
  for (int mt = 0; mt < 4; mt++) {
    int row = brow0 + mt * 16 + l15;
    row = row < N_ ? row : N_ - 1;
    bw[mt] = *(const bf16x8*)&n2vA[((long)row * 4 + l4) * 8];
  }

  f32x4 acc[4][3];
#pragma unroll
  for (int i = 0; i < 4; i++)
#pragma unroll
    for (int j = 0; j < 3; j++) acc[i][j] = f32x4{0.f, 0.f, 0.f, 0.f};
  float racc[4] = {0.f, 0.f, 0.f, 0.f};

#define PHASE_A(cexpr, slab)                                                              \
  {                                                                                       \
    const int c_ = (cexpr);                                                               \
    if (c_ < 313) {                                                                       \
      const int vb_ = c_ * 32;                                                            \
      int r1_ = vb_ + 16 + l15; r1_ = r1_ < N_ ? r1_ : N_ - 1;                            \
      bf16x8 av0_ = *(const bf16x8*)&n2vA[((long)(vb_ + l15) * 4 + l4) * 8];              \
      bf16x8 av1_ = *(const bf16x8*)&n2vA[((long)r1_ * 4 + l4) * 8];                      \
      _Pragma("unroll")                                                                   \
      for (int mt = 0; mt < 4; mt++) {                                                    \
        f32x4 s0_ = __builtin_amdgcn_mfma_f32_16x16x32_bf16(av0_, bw[mt],                 \
                                                            f32x4{0.f,0.f,0.f,0.f},0,0,0);\
        f32x4 s1_ = __builtin_amdgcn_mfma_f32_16x16x32_bf16(av1_, bw[mt],                 \
                                                            f32x4{0.f,0.f,0.f,0.f},0,0,0);\
        short pp_[8];                                                                     \
        float rs0_ = 0.f, rs1_ = 0.f;                                                     \
        _Pragma("unroll")                                                                 \
        for (int j = 0; j < 4; j++) {                                                     \
          float p0_ = EXP2F(fmaxf(s0_[j], 0.f));                                          \
          float p1_ = EXP2F(fmaxf(s1_[j], 0.f));                                          \
          if constexpr (PASS == 1) { rs0_ += p0_; rs1_ += p1_; }                          \
          pp_[j] = bf16c(p0_);                                                            \
          pp_[j + 4] = bf16c(p1_);                                                        \
        }                                                                                 \
        *(bf16x8*)&aPl[slab][((wv * 4 + mt) * 64 + lane) * 8] =                           \
            bf16x8{pp_[0],pp_[1],pp_[2],pp_[3],pp_[4],pp_[5],pp_[6],pp_[7]};              \
        if constexpr (PASS == 1) racc[mt] += (c_ != 312) ? (rs0_ + rs1_) : rs0_;          \
      }                                                                                   \
    }                                                                                     \
  }

  PHASE_A(wv, 0)
  __syncthreads();

  for (int g = 0; g < 40; g++) {
    const int cur = g & 1;
    if (g + 1 < 40) PHASE_A((g + 1) * 8 + wv, cur ^ 1)

    const int rem = 313 - g * 8;
    if (rem >= 8) {
      bf16x8 bx[24];
#pragma unroll
      for (int cc = 0; cc < 8; cc++) {
        const long xb = (long)(g * 8 + cc) * 1536 + (long)l4 * 384;
        bx[cc * 3 + 0] = *(const bf16x8*)&xq[(xb + colbase + 0 * 16 + l15) * 8];
        bx[cc * 3 + 1] = *(const bf16x8*)&xq[(xb + colbase + 1 * 16 + l15) * 8];
        bx[cc * 3 + 2] = *(const bf16x8*)&xq[(xb + colbase + 2 * 16 + l15) * 8];
      }
      __builtin_amdgcn_s_setprio(1);
#pragma unroll
      for (int cc = 0; cc < 8; cc++) {
#pragma unroll
        for (int mt = 0; mt < 4; mt++) {
          bf16x8 aP = *(const bf16x8*)&aPl[cur][((cc * 4 + mt) * 64 + lane) * 8];
          acc[mt][0] = __builtin_amdgcn_mfma_f32_16x16x32_bf16(aP, bx[cc * 3 + 0], acc[mt][0], 0, 0, 0);
          acc[mt][1] = __builtin_amdgcn_mfma_f32_16x16x32_bf16(aP, bx[cc * 3 + 1], acc[mt][1], 0, 0, 0);
          acc[mt][2] = __builtin_amdgcn_mfma_f32_16x16x32_bf16(aP, bx[cc * 3 + 2], acc[mt][2], 0, 0, 0);
        }
      }
      __builtin_amdgcn_s_setprio(0);
    } else {
      for (int cc = 0; cc < rem; cc++) {
        const long xb = (long)(g * 8 + cc) * 1536 + (long)l4 * 384;
        bf16x8 bx0 = *(const bf16x8*)&xq[(xb + colbase + 0 * 16 + l15) * 8];
        bf16x8 bx1 = *(const bf16x8*)&xq[(xb + colbase + 1 * 16 + l15) * 8];
        bf16x8 bx2 = *(const bf16x8*)&xq[(xb + colbase + 2 * 16 + l15) * 8];
#pragma unroll
        for (int mt = 0; mt < 4; mt++) {
          bf16x8 aP = *(const bf16x8*)&aPl[cur][((cc * 4 + mt) * 64 + lane) * 8];
          acc[mt][0] = __builtin_amdgcn_mfma_f32_16x16x32_bf16(aP, bx0, acc[mt][0], 0, 0, 0);
          acc[mt][1] = __builtin_amdgcn_mfma_f32_16x16x32_bf16(aP, bx1, acc[mt][1], 0, 0, 0);
          acc[mt][2] = __builtin_amdgcn_mfma_f32_16x16x32_bf16(aP, bx2, acc[mt][2], 0, 0, 0);
        }
      }
    }
    __syncthreads();
  }
#undef PHASE_A

  // plain stores: (block,wave) owns 64 rows x its 48 cols exclusively (both passes)
#pragma unroll
  for (int mt = 0; mt < 4; mt++) {
#pragma unroll
    for (int nt = 0; nt < 3; nt++) {
      const int col = colbase + nt * 16 + l15;
      const int t = col >> 5, f = col & 31;
#pragma unroll
      for (int j = 0; j < 4; j++) {
        const int w = brow0 + mt * 16 + 4 * l4 + j;
        if (w < N_) out[((long)t * N_ + w) * 32 + f] = acc[mt][nt][j];
      }
    }
  }

  if constexpr (PASS == 1) {
    // ---- block-local R reduction (aPl dead after main loop; reuse as float slab) ----
    float* Rsh = (float*)aPl;          // [8 waves][64 rows]
    float* Rinvsh = (float*)aPl + 512; // [64 rows]
    float rpart[4];
#pragma unroll
    for (int mt = 0; mt < 4; mt++) {
      float r = racc[mt];
      r += __shfl_xor(r, 16, 64);
      r += __shfl_xor(r, 32, 64);     // every lane now holds the sum for row mt*16+l15
      rpart[mt] = r;
    }
    __syncthreads();                   // ensure all waves done reading aPl
    if (l4 == 0) {
#pragma unroll
      for (int mt = 0; mt < 4; mt++) Rsh[wv * 64 + mt * 16 + l15] = rpart[mt];
    }
    __syncthreads();
    if (tid < 64) {
      float s = 0.f;
#pragma unroll
      for (int w8 = 0; w8 < 8; w8++) s += Rsh[w8 * 64 + tid];
      float ri = 1.f / s;
      Rinvsh[tid] = ri;
      int w = brow0 + tid;
      if (w < N_) Rout[w] = ri;        // Rout stores rinv directly
    }
    __syncthreads();
    // ---- pack xq1 straight from registers: entry (ck,l4,col) = rows of mt pair ----
#pragma unroll
    for (int ckh = 0; ckh < 2; ckh++) {
      const int ck = (brow0 >> 5) + ckh;
      if (ck < 313) {
#pragma unroll
        for (int nt = 0; nt < 3; nt++) {
          const int col = colbase + nt * 16 + l15;
          short pv[8];
#pragma unroll
          for (int half = 0; half < 2; half++) {
            const int mt = 2 * ckh + half;
#pragma unroll
            for (int j = 0; j < 4; j++) {
              const int rloc = mt * 16 + 4 * l4 + j;
              const int w = brow0 + rloc;
              float val = (w < N_) ? acc[mt][nt][j] * Rinvsh[rloc] : 0.f;
              pv[half * 4 + j] = bf16c(val);
            }
          }
          *(bf16x8*)&xqout[(((long)ck * 4 + l4) * 384 + col) * 8] =
              bf16x8{pv[0], pv[1], pv[2], pv[3], pv[4], pv[5], pv[6], pv[7]};
        }
      }
    }
  }
}

// ---------------- x_adp = [x, x1*rinv, x2*rinv] @ gcn_w + gcn_b (in-place over x2) -----
__global__ __launch_bounds__(256) void k_gcn(const float* __restrict__ x,
                                             const float* __restrict__ x1,
                                             float* __restrict__ x2io,
                                             const float* __restrict__ Rinv,
                                             const float* __restrict__ gcn_w,
                                             const float* __restrict__ gcn_b) {
  __shared__ float W[96 * 32];
  __shared__ float bsh[32];
  __shared__ float rows[8][96];
  int tid = threadIdx.x;
  for (int i = tid; i < 96 * 32; i += 256) W[i] = gcn_w[i];
  if (tid < 32) bsh[tid] = gcn_b[tid];
  long base = (long)blockIdx.x * 8;
  int nloc = tid >> 5, c = tid & 31;
  long row = base + nloc;
  long nIdx = row % N_;
  float ri = Rinv[nIdx];
  rows[nloc][c] = x[row * 32 + c];
  rows[nloc][32 + c] = x1[row * 32 + c] * ri;
  rows[nloc][64 + c] = x2io[row * 32 + c] * ri;
  __syncthreads();
  float o = bsh[c];
#pragma unroll
  for (int k = 0; k < 96; k++) o = fmaf(rows[nloc][k], W[k * 32 + c], o);
  __syncthreads();
  x2io[row * 32 + c] = o;
}

// ---------------- collapsed slot attention + mean + elu (original, best measured) ------
__device__ __forceinline__ void load_row(int s, long r, const float* __restrict__ x,
                                         const __hip_bfloat16* __restrict__ hp16,
                                         const float* __restrict__ xadp, float* m) {
  if (s == 0 || s == 4) {
    const float4* p = (const float4*)((s == 0 ? x : xadp) + r * 32);
#pragma unroll
    for (int q = 0; q < 8; q++) {
      float4 v = p[q];
      m[q * 4 + 0] = v.x; m[q * 4 + 1] = v.y; m[q * 4 + 2] = v.z; m[q * 4 + 3] = v.w;
    }
  } else {
    const uint4* p = (const uint4*)(hp16 + ((long)(s - 1) * TN_ + r) * 32);
#pragma unroll
    for (int q = 0; q < 4; q++) {
      uint4 v = p[q];
      unsigned uu[4] = {v.x, v.y, v.z, v.w};
#pragma unroll
      for (int j = 0; j < 4; j++) {
        m[q * 8 + j * 2 + 0] = __uint_as_float(uu[j] << 16);
        m[q * 8 + j * 2 + 1] = __uint_as_float(uu[j] & 0xffff0000u);
      }
    }
  }
}

__global__ __launch_bounds__(256) void k_attn(const float* __restrict__ x,
                                              const __hip_bfloat16* __restrict__ hp16,
                                              const float* __restrict__ xadp,
                                              const float* __restrict__ prm,
                                              float* __restrict__ out) {
  __shared__ float Gs[1024], Hs[1024], g1s[32], g2s[32], hbs[32];
  __shared__ float g0sh;
  int tid = threadIdx.x;
  for (int i = tid; i < 1024; i += 256) { Gs[i] = prm[PRM_G + i]; Hs[i] = prm[PRM_H + i]; }
  if (tid < 32) { g1s[tid] = prm[PRM_G1 + tid]; g2s[tid] = prm[PRM_G2 + tid]; hbs[tid] = prm[PRM_HB + tid]; }
  if (tid == 0) g0sh = prm[PRM_G0];
  __syncthreads();
  long r = (long)blockIdx.x * 256 + tid;
  if (r >= TN_) return;
  float g0 = g0sh;
  float sc[5][5], d1[5], d2[5];
  float ms[32], mu[32], y[32];
#pragma unroll
  for (int s = 0; s < 5; s++) {
    load_row(s, r, x, hp16, xadp, ms);
    float a = 0.f, b = 0.f;
#pragma unroll
    for (int k = 0; k < 32; k++) { a = fmaf(ms[k], g1s[k], a); b = fmaf(ms[k], g2s[k], b); }
    d1[s] = a; d2[s] = b;
#pragma unroll
    for (int c = 0; c < 32; c++) {
      float s2 = 0.f;
#pragma unroll
      for (int k = 0; k < 32; k++) s2 = fmaf(ms[k], Gs[k * 32 + c], s2);
      y[c] = s2;
    }
#pragma unroll
    for (int u = 0; u < 5; u++) {
      load_row(u, r, x, hp16, xadp, mu);
      float dt = 0.f;
#pragma unroll
      for (int k = 0; k < 32; k++) dt = fmaf(y[k], mu[k], dt);
      sc[s][u] = dt;
    }
  }
  const float rs = 0.07216878364870322f;  // 1/sqrt(192)
  float abar[5];
#pragma unroll
  for (int u = 0; u < 5; u++) abar[u] = 0.f;
#pragma unroll
  for (int s = 0; s < 5; s++) {
    float e[5];
    float mx = -1e30f;
#pragma unroll
    for (int u = 0; u < 5; u++) {
      float v = (sc[s][u] + d1[s] + d2[u] + g0) * rs;
      e[u] = v;
      mx = fmaxf(mx, v);
    }
    float sm = 0.f;
#pragma unroll
    for (int u = 0; u < 5; u++) { e[u] = __expf(e[u] - mx); sm += e[u]; }
    float inv = 1.f / sm;
#pragma unroll
    for (int u = 0; u < 5; u++) abar[u] = fmaf(e[u], inv, abar[u]);
  }
  float z[32];
#pragma unroll
  for (int k = 0; k < 32; k++) z[k] = 0.f;
#pragma unroll
  for (int u = 0; u < 5; u++) {
    load_row(u, r, x, hp16, xadp, mu);
    float w = abar[u] * 0.2f;
#pragma unroll
    for (int k = 0; k < 32; k++) z[k] = fmaf(w, mu[k], z[k]);
  }
#pragma unroll
  for (int c = 0; c < 32; c++) {
    float o = hbs[c];
#pragma unroll
    for (int k = 0; k < 32; k++) o = fmaf(z[k], Hs[k * 32 + c], o);
    o = (o > 0.f) ? o : (__expf(o) - 1.f);
    out[r * 32 + c] = o;
  }
}

// ---------------- launch ----------------
extern "C" void kernel_launch(void* const* d_in, const int* in_sizes, int n_in,
                              void* d_out, int out_size, void* d_ws, size_t ws_size,
                              hipStream_t stream) {
  (void)in_sizes; (void)n_in; (void)out_size; (void)ws_size;
  const float* x          = (const float*)d_in[0];
  const float* timeoh     = (const float*)d_in[1];
  const int*   edges      = (const int*)d_in[2];
  const float* mlp_w      = (const float*)d_in[3];
  const float* mlp_b      = (const float*)d_in[4];
  const float* temb_w     = (const float*)d_in[5];
  const float* atten_pool = (const float*)d_in[6];
  const float* node2vec   = (const float*)d_in[7];
  const float* gcn_w      = (const float*)d_in[8];
  const float* gcn_b      = (const float*)d_in[9];
  const float* q_w  = (const float*)d_in[10];
  const float* q_b  = (const float*)d_in[11];
  const float* k_w  = (const float*)d_in[12];
  const float* k_b  = (const float*)d_in[13];
  const float* v_w  = (const float*)d_in[14];
  const float* v_b  = (const float*)d_in[15];
  const float* dense_w = (const float*)d_in[16];
  const float* dense_b = (const float*)d_in[17];
  float* out = (float*)d_out;
  char* ws = (char*)d_ws;

  float*    prm  = (float*)(ws + 0);
  float*    Mt   = (float*)(ws + 9216);
  int*      cnt  = (int*)(ws + 9472);
  int*      cur  = (int*)(ws + 129472);
  int*      offs = (int*)(ws + 249472);
  float*    ssrc = (float*)(ws + 369664);
  float*    sdst = (float*)(ws + 849664);
  float*    R    = (float*)(ws + 1329664);
  __hip_bfloat16* h16  = (__hip_bfloat16*)(ws + 1369664);
  int*      csr  = (int*)(ws + 9049664);
  __hip_bfloat16* hp16 = (__hip_bfloat16*)(ws + 12889664);
  float*    x1   = (float*)(ws + 35929664);
  float*    x2   = (float*)(ws + 51289664);
  short*    n2vA = (short*)(ws + 66649664);   //   640,000 B
  short*    xq0  = (short*)(ws + 67289664);   // 7,692,288 B
  short*    xq1  = (short*)(ws + 74983488);   // 7,692,288 B

  (void)hipMemsetAsync(cnt, 0, 120000, stream);

  k_prep<<<1, 256, 0, stream>>>(timeoh, temb_w, atten_pool, q_w, q_b, k_w, k_b,
                                v_w, v_b, dense_w, dense_b, prm);
  k_h<<<15000, 256, 0, stream>>>(x, mlp_w, mlp_b, prm, h16, ssrc, sdst);
  k_maxs<<<12, 256, 0, stream>>>(ssrc, sdst, Mt);
  k_hist<<<dim3(1250, 3), 256, 0, stream>>>(edges, cnt);
  k_scan<<<3, 1024, 0, stream>>>(cnt, offs, cur);
  k_fill<<<dim3(1250, 3), 256, 0, stream>>>(edges, cur, csr);
  k_gather<<<dim3(2500, 3), 256, 0, stream>>>(csr, offs, ssrc, sdst, Mt, h16, hp16);

  k_n2vA<<<157, 256, 0, stream>>>(node2vec, n2vA);
  k_pack0<<<1878, 256, 0, stream>>>(x, xq0);
  k_adj12<1><<<157, 512, 0, stream>>>(n2vA, xq0, x1, R, xq1);
  k_adj12<2><<<157, 512, 0, stream>>>(n2vA, xq1, x2, nullptr, nullptr);
  k_gcn<<<15000, 256, 0, stream>>>(x, x1, x2, R, gcn_w, gcn_b);
  k_attn<<<469, 256, 0, stream>>>(x, hp16, x2, prm, out);
}

// Round 26
// 750.172 us; speedup vs baseline: 1.3622x; 1.0120x over previous
//
#include <hip/hip_runtime.h>
#include <hip/hip_bf16.h>

#define T_ 12
#define N_ 10000
#define C_ 32
#define E_ 320000
#define SUP_ 3
#define TN_ (T_*N_)

typedef __attribute__((ext_vector_type(4))) float f32x4;
typedef __attribute__((ext_vector_type(8))) short bf16x8;
typedef __attribute__((ext_vector_type(4))) short bf16x4;

__device__ __forceinline__ short bf16c(float f) {
  __hip_bfloat16 b = __float2bfloat16(f);
  return (short)__builtin_bit_cast(unsigned short, b);
}

#if __has_builtin(__builtin_amdgcn_exp2f)
#define EXP2F(x) __builtin_amdgcn_exp2f(x)
#else
#define EXP2F(x) exp2f(x)
#endif

// prm layout (float offsets)
#define PRM_ATTN 0
#define PRM_G    64
#define PRM_H    1088
#define PRM_G1   2112
#define PRM_G2   2144
#define PRM_HB   2176
#define PRM_G0   2208

// ---------------- small precompute: attn vector + folded attention mats ----------------
__global__ __launch_bounds__(256) void k_prep(
    const float* __restrict__ timeoh, const float* __restrict__ temb_w,
    const float* __restrict__ atten_pool,
    const float* __restrict__ q_w, const float* __restrict__ q_b,
    const float* __restrict__ k_w, const float* __restrict__ k_b,
    const float* __restrict__ v_w, const float* __restrict__ v_b,
    const float* __restrict__ dense_w, const float* __restrict__ dense_b,
    float* __restrict__ prm) {
  __shared__ float tv[8];
  int tid = threadIdx.x;
  if (tid < 8) {
    float s = 0.f;
    for (int j = 0; j < 43; j++) s += timeoh[j] * temb_w[j * 8 + tid];
    tv[tid] = s;
  }
  __syncthreads();
  if (tid < 64) {
    float s = 0.f;
    for (int d = 0; d < 8; d++) s += tv[d] * atten_pool[d * 64 + tid];
    prm[PRM_ATTN + tid] = s;
  }
  for (int idx = tid; idx < 1024; idx += 256) {
    int r = idx >> 5, c = idx & 31;
    float s = 0.f, s2 = 0.f;
    for (int d = 0; d < 192; d++) {
      s  += q_w[r * 192 + d] * k_w[c * 192 + d];    // G = q_w @ k_w^T
      s2 += v_w[r * 192 + d] * dense_w[d * 32 + c]; // H = v_w @ dense_w
    }
    prm[PRM_G + idx] = s;
    prm[PRM_H + idx] = s2;
  }
  if (tid < 32) {
    float s = 0.f, s2 = 0.f, s3 = 0.f;
    for (int d = 0; d < 192; d++) {
      s  += q_w[tid * 192 + d] * k_b[d];
      s2 += k_w[tid * 192 + d] * q_b[d];
      s3 += v_b[d] * dense_w[d * 32 + tid];
    }
    prm[PRM_G1 + tid] = s;
    prm[PRM_G2 + tid] = s2;
    prm[PRM_HB + tid] = s3 + dense_b[tid];
  }
  if (tid == 0) {
    float s = 0.f;
    for (int d = 0; d < 192; d++) s += q_b[d] * k_b[d];
    prm[PRM_G0] = s;
  }
}

// ---------------- h = x@mlp_w+mlp_b (bf16, n-major [n][t][c]), s_src/s_dst [n][t] -------
__global__ __launch_bounds__(256) void k_h(
    const float* __restrict__ x, const float* __restrict__ mlp_w,
    const float* __restrict__ mlp_b, const float* __restrict__ prm,
    __hip_bfloat16* __restrict__ h16t, float* __restrict__ s_srct,
    float* __restrict__ s_dstt) {
  __shared__ float W[32 * 32];
  __shared__ float bsh[32], attnsh[64];
  __shared__ float xs[8][32];
  int tid = threadIdx.x;
  for (int i = tid; i < 1024; i += 256) W[i] = mlp_w[i];
  if (tid < 32) bsh[tid] = mlp_b[tid];
  if (tid < 64) attnsh[tid] = prm[PRM_ATTN + tid];
  long base = (long)blockIdx.x * 8;
  int nloc = tid >> 5, c = tid & 31;
  long row = base + nloc;  // flat t*N+n, grid sized exactly
  const int t = (int)(row / N_);
  const int n = (int)(row - (long)t * N_);
  xs[nloc][c] = x[row * 32 + c];
  __syncthreads();
  float hval = bsh[c];
#pragma unroll
  for (int k = 0; k < 32; k++) hval = fmaf(xs[nloc][k], W[k * 32 + c], hval);
  h16t[((long)n * 12 + t) * 32 + c] = __float2bfloat16(hval);
  float a = hval * attnsh[c], b = hval * attnsh[32 + c];
#pragma unroll
  for (int m = 16; m >= 1; m >>= 1) {
    a += __shfl_xor(a, m, 64);
    b += __shfl_xor(b, m, 64);
  }
  if (c == 0) { s_srct[(long)n * 12 + t] = a; s_dstt[(long)n * 12 + t] = b; }
}

// ---------------- per-t shift bound: M[t] = max_n ssrct + max_n sdstt -------------------
__global__ __launch_bounds__(256) void k_maxs(const float* __restrict__ ssrct,
                                              const float* __restrict__ sdstt,
                                              float* __restrict__ Mt) {
  __shared__ float sh[8];
  const int t = blockIdx.x, tid = threadIdx.x;
  float ma = -1e30f, mb = -1e30f;
  for (int i = tid; i < N_; i += 256) {
    ma = fmaxf(ma, ssrct[(long)i * 12 + t]);
    mb = fmaxf(mb, sdstt[(long)i * 12 + t]);
  }
#pragma unroll
  for (int k = 32; k >= 1; k >>= 1) {
    ma = fmaxf(ma, __shfl_xor(ma, k, 64));
    mb = fmaxf(mb, __shfl_xor(mb, k, 64));
  }
  if ((tid & 63) == 0) { sh[(tid >> 6) * 2] = ma; sh[(tid >> 6) * 2 + 1] = mb; }
  __syncthreads();
  if (tid == 0) {
    float A = fmaxf(fmaxf(sh[0], sh[2]), fmaxf(sh[4], sh[6]));
    float B = fmaxf(fmaxf(sh[1], sh[3]), fmaxf(sh[5], sh[7]));
    Mt[t] = A + B;
  }
}

// ---------------- CSR build ----------------
__global__ __launch_bounds__(256) void k_hist(const int* __restrict__ edges,
                                              int* __restrict__ cnt) {
  int sup = blockIdx.y;
  int e = blockIdx.x * 256 + threadIdx.x;
  const int* src = edges + (long)sup * 2 * E_;
  atomicAdd(&cnt[sup * N_ + src[e]], 1);
}

// single-pass scan: each of 1024 threads owns 10 elements (serial), one 1024-wide
// Hillis-Steele scan (10 steps), serial prefix write-out. ~10x fewer barrier phases.
__global__ __launch_bounds__(1024) void k_scan(const int* __restrict__ cnt,
                                               int* __restrict__ offs,
                                               int* __restrict__ cur) {
  __shared__ int sh[1024];
  const int sup = blockIdx.x, tid = threadIdx.x;
  const int base = tid * 10;
  int loc[10];
  int s = 0;
#pragma unroll
  for (int j = 0; j < 10; j++) {
    int i = base + j;
    int v = (i < N_) ? cnt[sup * N_ + i] : 0;
    loc[j] = v;
    s += v;
  }
  sh[tid] = s;
  __syncthreads();
  for (int off = 1; off < 1024; off <<= 1) {
    int t = (tid >= off) ? sh[tid - off] : 0;
    __syncthreads();
    sh[tid] += t;
    __syncthreads();
  }
  int excl = sh[tid] - s;
#pragma unroll
  for (int j = 0; j < 10; j++) {
    int i = base + j;
    if (i < N_) {
      offs[sup * (N_ + 1) + i] = excl;
      cur[sup * N_ + i] = excl;
    }
    excl += loc[j];
  }
  if (tid == 1023) offs[sup * (N_ + 1) + N_] = excl;  // = total (tail lanes add 0)
}

__global__ __launch_bounds__(256) void k_fill(const int* __restrict__ edges,
                                              int* __restrict__ cur,
                                              int* __restrict__ csr) {
  int sup = blockIdx.y;
  int e = blockIdx.x * 256 + threadIdx.x;
  const int* src = edges + (long)sup * 2 * E_;
  const int* dst = src + E_;
  int pos = atomicAdd(&cur[sup * N_ + src[e]], 1);
  csr[sup * E_ + pos] = dst[e];
}

// ---------------- GAT gather v3: wave per (sup,n), ALL 12 t at once --------------------
__global__ __launch_bounds__(256) void k_gather(
    const int* __restrict__ csr, const int* __restrict__ offs,
    const float* __restrict__ s_srct, const float* __restrict__ s_dstt,
    const float* __restrict__ Mt, const __hip_bfloat16* __restrict__ h16t,
    __hip_bfloat16* __restrict__ hp16) {
  const int sup = blockIdx.y;
  const int wave = threadIdx.x >> 6, lane = threadIdx.x & 63;
  const int n = blockIdx.x * 4 + wave;
  const int tg = (lane < 48) ? (lane >> 2) : 0;   // t group (lanes 48+ mirror tg=0)
  const int cl = lane & 3;                         // 16B slice of the row
  const float at = s_srct[(long)n * 12 + tg];
  const float Mv = Mt[tg];
  const int off = offs[sup * (N_ + 1) + n], end = offs[sup * (N_ + 1) + n + 1];
  const uint4* hb4 = (const uint4*)h16t;
  const int* csrs = csr + sup * E_;
  const int clamp = (end > off) ? (end - 1) : 0;

  float acc[8];
#pragma unroll
  for (int j = 0; j < 8; j++) acc[j] = 0.f;
  float psum = 0.f;

  int d0 = csrs[min(off, clamp)];
  int d1 = csrs[min(off + 1, clamp)];
  float sd0 = s_dstt[(long)d0 * 12 + tg];
  uint4 u0 = hb4[((long)d0 * 12 + tg) * 4 + cl];

  for (int idx = off; idx < end; idx++) {
    int d2 = csrs[min(idx + 2, clamp)];            // two ahead
    float sd1 = s_dstt[(long)d1 * 12 + tg];        // one ahead
    uint4 u1 = hb4[((long)d1 * 12 + tg) * 4 + cl];
    float v = at + sd0;
    v = fmaxf(v, 0.01f * v);                       // leaky
    float p = __expf(v - Mv);
    psum += p;
    acc[0] = fmaf(p, __uint_as_float(u0.x << 16),         acc[0]);
    acc[1] = fmaf(p, __uint_as_float(u0.x & 0xffff0000u), acc[1]);
    acc[2] = fmaf(p, __uint_as_float(u0.y << 16),         acc[2]);
    acc[3] = fmaf(p, __uint_as_float(u0.y & 0xffff0000u), acc[3]);
    acc[4] = fmaf(p, __uint_as_float(u0.z << 16),         acc[4]);
    acc[5] = fmaf(p, __uint_as_float(u0.z & 0xffff0000u), acc[5]);
    acc[6] = fmaf(p, __uint_as_float(u0.w << 16),         acc[6]);
    acc[7] = fmaf(p, __uint_as_float(u0.w & 0xffff0000u), acc[7]);
    d1 = d2; sd0 = sd1; u0 = u1;
  }

  if (lane < 48) {   // write-only epilogue: lane owns (t=tg, cols cl*8..cl*8+7)
    float inv = 1.f / (psum + 9e-15f);
    unsigned w[4];
#pragma unroll
    for (int q = 0; q < 4; q++) {
      float h0 = acc[2 * q + 0] * inv;
      float h1 = acc[2 * q + 1] * inv;
      h0 = (h0 > 0.f) ? h0 : (__expf(h0) - 1.f);
      h1 = (h1 > 0.f) ? h1 : (__expf(h1) - 1.f);
      unsigned lo = (unsigned)(unsigned short)__builtin_bit_cast(unsigned short, __float2bfloat16(h0));
      unsigned hi = (unsigned)(unsigned short)__builtin_bit_cast(unsigned short, __float2bfloat16(h1));
      w[q] = lo | (hi << 16);
    }
    ((uint4*)hp16)[((long)sup * TN_ + (long)tg * N_ + n) * 4 + cl] = uint4{w[0], w[1], w[2], w[3]};
  }
}

// ---------------- n2v -> bf16 frag-packed, PRE-SCALED by sqrt(log2 e) ------------------
__global__ __launch_bounds__(256) void k_n2vA(const float* __restrict__ n2v,
                                              short* __restrict__ n2vA) {
  const float SC = 1.2011224087864498f;  // sqrt(log2(e))
  int idx = blockIdx.x * 256 + threadIdx.x;
  if (idx >= N_ * 4) return;
  int row = idx >> 2, l4 = idx & 3;
  short v[8];
#pragma unroll
  for (int h = 0; h < 2; h++)
#pragma unroll
    for (int j = 0; j < 4; j++)
      v[h * 4 + j] = bf16c(n2v[row * 32 + 16 * h + 4 * l4 + j] * SC);
  *(bf16x8*)&n2vA[(long)idx * 8] = bf16x8{v[0], v[1], v[2], v[3], v[4], v[5], v[6], v[7]};
}

// ---------------- pack X f32 -> B-frag layout bf16 (pass-0 only; pass-1 fused) ---------
__global__ __launch_bounds__(256) void k_pack0(const float* __restrict__ src,
                                               short* __restrict__ xq) {
  int idx = blockIdx.x * 256 + threadIdx.x;  // 313*4*384 = 480768 exact
  int ck = idx / 1536;
  int rem = idx - ck * 1536;
  int l4 = rem / 384;
  int col = rem - l4 * 384;
  int t = col >> 5, f = col & 31;
  const long cb = (long)t * N_ * 32 + f;
  short v[8];
#pragma unroll
  for (int e = 0; e < 8; e++) {
    int vv = ck * 32 + 4 * l4 + (e & 3) + 16 * (e >> 2);
    float a = 0.f;
    if (vv < N_) a = src[cb + (long)vv * 32];
    v[e] = bf16c(a);
  }
  *(bf16x8*)&xq[(long)idx * 8] = bf16x8{v[0], v[1], v[2], v[3], v[4], v[5], v[6], v[7]};
}

// ---------------- MFMA fused adj@X: LDS-shared aP, ping-pong, batched bx, T5 setprio ---
// PASS 1 extra fusion: block-local R -> rinv written directly; xq1 packed from registers.
template <int PASS>
__global__ __launch_bounds__(512, 2) void k_adj12(const short* __restrict__ n2vA,
                                                  const short* __restrict__ xq,
                                                  float* __restrict__ out,
                                                  float* __restrict__ Rout,
                                                  short* __restrict__ xqout) {
  __shared__ __align__(16) short aPl[2][8 * 4 * 64 * 8];  // 2 x 32 KB ping-pong
  const int tid = threadIdx.x;
  const int lane = tid & 63;
  const int wv = tid >> 6;       // 0..7 : colgroup in phase B, chunk-slot in phase A
  const int l15 = lane & 15;
  const int l4 = lane >> 4;      // 0..3
  const int brow0 = blockIdx.x * 64;
  const int colbase = wv * 48;

  bf16x8 bw[4];
#pragma unroll
  for (int mt = 0; mt < 4; mt++) {
    int row = brow0 + mt * 16 + l15;
    row = row < N_ ? row : N_ - 1;
    bw[mt] = *(const bf16x8*)&n2vA[((long)row * 4 + l4) * 8];
  }

  f32x4 acc[4][3];
#pragma unroll
  for (int i = 0; i < 4; i++)
#pragma unroll
    for (int j = 0; j < 3; j++) acc[i][j] = f32x4{0.f, 0.f, 0.f, 0.f};
  float racc[4] = {0.f, 0.f, 0.f, 0.f};

#define PHASE_A(cexpr, slab)                                                              \
  {                                                                                       \
    const int c_ = (cexpr);                                                               \
    if (c_ < 313) {                                                                       \
      const int vb_ = c_ * 32;                                                            \
      int r1_ = vb_ + 16 + l15; r1_ = r1_ < N_ ? r1_ : N_ - 1;                            \
      bf16x8 av0_ = *(const bf16x8*)&n2vA[((long)(vb_ + l15) * 4 + l4) * 8];              \
      bf16x8 av1_ = *(const bf16x8*)&n2vA[((long)r1_ * 4 + l4) * 8];                      \
      _Pragma("unroll")                                                                   \
      for (int mt = 0; mt < 4; mt++) {                                                    \
        f32x4 s0_ = __builtin_amdgcn_mfma_f32_16x16x32_bf16(av0_, bw[mt],                 \
                                                            f32x4{0.f,0.f,0.f,0.f},0,0,0);\
        f32x4 s1_ = __builtin_amdgcn_mfma_f32_16x16x32_bf16(av1_, bw[mt],                 \
                                                            f32x4{0.f,0.f,0.f,0.f},0,0,0);\
        short pp_[8];                                                                     \
        float rs0_ = 0.f, rs1_ = 0.f;                                                     \
        _Pragma("unroll")                                                                 \
        for (int j = 0; j < 4; j++) {                                                     \
          float p0_ = EXP2F(fmaxf(s0_[j], 0.f));                                          \
          float p1_ = EXP2F(fmaxf(s1_[j], 0.f));                                          \
          if constexpr (PASS == 1) { rs0_ += p0_; rs1_ += p1_; }                          \
          pp_[j] = bf16c(p0_);                                                            \
          pp_[j + 4] = bf16c(p1_);                                                        \
        }                                                                                 \
        *(bf16x8*)&aPl[slab][((wv * 4 + mt) * 64 + lane) * 8] =                           \
            bf16x8{pp_[0],pp_[1],pp_[2],pp_[3],pp_[4],pp_[5],pp_[6],pp_[7]};              \
        if constexpr (PASS == 1) racc[mt] += (c_ != 312) ? (rs0_ + rs1_) : rs0_;          \
      }                                                                                   \
    }                                                                                     \
  }

  PHASE_A(wv, 0)
  __syncthreads();

  for (int g = 0; g < 40; g++) {
    const int cur = g & 1;
    if (g + 1 < 40) PHASE_A((g + 1) * 8 + wv, cur ^ 1)

    const int rem = 313 - g * 8;
    if (rem >= 8) {
      bf16x8 bx[24];
#pragma unroll
      for (int cc = 0; cc < 8; cc++) {
        const long xb = (long)(g * 8 + cc) * 1536 + (long)l4 * 384;
        bx[cc * 3 + 0] = *(const bf16x8*)&xq[(xb + colbase + 0 * 16 + l15) * 8];
        bx[cc * 3 + 1] = *(const bf16x8*)&xq[(xb + colbase + 1 * 16 + l15) * 8];
        bx[cc * 3 + 2] = *(const bf16x8*)&xq[(xb + colbase + 2 * 16 + l15) * 8];
      }
      __builtin_amdgcn_s_setprio(1);
#pragma unroll
      for (int cc = 0; cc < 8; cc++) {
#pragma unroll
        for (int mt = 0; mt < 4; mt++) {
          bf16x8 aP = *(const bf16x8*)&aPl[cur][((cc * 4 + mt) * 64 + lane) * 8];
          acc[mt][0] = __builtin_amdgcn_mfma_f32_16x16x32_bf16(aP, bx[cc * 3 + 0], acc[mt][0], 0, 0, 0);
          acc[mt][1] = __builtin_amdgcn_mfma_f32_16x16x32_bf16(aP, bx[cc * 3 + 1], acc[mt][1], 0, 0, 0);
          acc[mt][2] = __builtin_amdgcn_mfma_f32_16x16x32_bf16(aP, bx[cc * 3 + 2], acc[mt][2], 0, 0, 0);
        }
      }
      __builtin_amdgcn_s_setprio(0);
    } else {
      for (int cc = 0; cc < rem; cc++) {
        const long xb = (long)(g * 8 + cc) * 1536 + (long)l4 * 384;
        bf16x8 bx0 = *(const bf16x8*)&xq[(xb + colbase + 0 * 16 + l15) * 8];
        bf16x8 bx1 = *(const bf16x8*)&xq[(xb + colbase + 1 * 16 + l15) * 8];
        bf16x8 bx2 = *(const bf16x8*)&xq[(xb + colbase + 2 * 16 + l15) * 8];
#pragma unroll
        for (int mt = 0; mt < 4; mt++) {
          bf16x8 aP = *(const bf16x8*)&aPl[cur][((cc * 4 + mt) * 64 + lane) * 8];
          acc[mt][0] = __builtin_amdgcn_mfma_f32_16x16x32_bf16(aP, bx0, acc[mt][0], 0, 0, 0);
          acc[mt][1] = __builtin_amdgcn_mfma_f32_16x16x32_bf16(aP, bx1, acc[mt][1], 0, 0, 0);
          acc[mt][2] = __builtin_amdgcn_mfma_f32_16x16x32_bf16(aP, bx2, acc[mt][2], 0, 0, 0);
        }
      }
    }
    __syncthreads();
  }
#undef PHASE_A

  // plain stores: (block,wave) owns 64 rows x its 48 cols exclusively (both passes)
#pragma unroll
  for (int mt = 0; mt < 4; mt++) {
#pragma unroll
    for (int nt = 0; nt < 3; nt++) {
      const int col = colbase + nt * 16 + l15;
      const int t = col >> 5, f = col & 31;
#pragma unroll
      for (int j = 0; j < 4; j++) {
        const int w = brow0 + mt * 16 + 4 * l4 + j;
        if (w < N_) out[((long)t * N_ + w) * 32 + f] = acc[mt][nt][j];
      }
    }
  }

  if constexpr (PASS == 1) {
    // ---- block-local R reduction (aPl dead after main loop; reuse as float slab) ----
    float* Rsh = (float*)aPl;          // [8 waves][64 rows]
    float* Rinvsh = (float*)aPl + 512; // [64 rows]
    float rpart[4];
#pragma unroll
    for (int mt = 0; mt < 4; mt++) {
      float r = racc[mt];
      r += __shfl_xor(r, 16, 64);
      r += __shfl_xor(r, 32, 64);     // every lane now holds the sum for row mt*16+l15
      rpart[mt] = r;
    }
    __syncthreads();                   // ensure all waves done reading aPl
    if (l4 == 0) {
#pragma unroll
      for (int mt = 0; mt < 4; mt++) Rsh[wv * 64 + mt * 16 + l15] = rpart[mt];
    }
    __syncthreads();
    if (tid < 64) {
      float s = 0.f;
#pragma unroll
      for (int w8 = 0; w8 < 8; w8++) s += Rsh[w8 * 64 + tid];
      float ri = 1.f / s;
      Rinvsh[tid] = ri;
      int w = brow0 + tid;
      if (w < N_) Rout[w] = ri;        // Rout stores rinv directly
    }
    __syncthreads();
    // ---- pack xq1 straight from registers: entry (ck,l4,col) = rows of mt pair ----
#pragma unroll
    for (int ckh = 0; ckh < 2; ckh++) {
      const int ck = (brow0 >> 5) + ckh;
      if (ck < 313) {
#pragma unroll
        for (int nt = 0; nt < 3; nt++) {
          const int col = colbase + nt * 16 + l15;
          short pv[8];
#pragma unroll
          for (int half = 0; half < 2; half++) {
            const int mt = 2 * ckh + half;
#pragma unroll
            for (int j = 0; j < 4; j++) {
              const int rloc = mt * 16 + 4 * l4 + j;
              const int w = brow0 + rloc;
              float val = (w < N_) ? acc[mt][nt][j] * Rinvsh[rloc] : 0.f;
              pv[half * 4 + j] = bf16c(val);
            }
          }
          *(bf16x8*)&xqout[(((long)ck * 4 + l4) * 384 + col) * 8] =
              bf16x8{pv[0], pv[1], pv[2], pv[3], pv[4], pv[5], pv[6], pv[7]};
        }
      }
    }
  }
}

// ---------------- x_adp = [x, x1*rinv, x2*rinv] @ gcn_w + gcn_b (in-place over x2) -----
__global__ __launch_bounds__(256) void k_gcn(const float* __restrict__ x,
                                             const float* __restrict__ x1,
                                             float* __restrict__ x2io,
                                             const float* __restrict__ Rinv,
                                             const float* __restrict__ gcn_w,
                                             const float* __restrict__ gcn_b) {
  __shared__ float W[96 * 32];
  __shared__ float bsh[32];
  __shared__ float rows[8][96];
  int tid = threadIdx.x;
  for (int i = tid; i < 96 * 32; i += 256) W[i] = gcn_w[i];
  if (tid < 32) bsh[tid] = gcn_b[tid];
  long base = (long)blockIdx.x * 8;
  int nloc = tid >> 5, c = tid & 31;
  long row = base + nloc;
  long nIdx = row % N_;
  float ri = Rinv[nIdx];
  rows[nloc][c] = x[row * 32 + c];
  rows[nloc][32 + c] = x1[row * 32 + c] * ri;
  rows[nloc][64 + c] = x2io[row * 32 + c] * ri;
  __syncthreads();
  float o = bsh[c];
#pragma unroll
  for (int k = 0; k < 96; k++) o = fmaf(rows[nloc][k], W[k * 32 + c], o);
  __syncthreads();
  x2io[row * 32 + c] = o;
}

// ---------------- collapsed slot attention + mean + elu (original, best measured) ------
__device__ __forceinline__ void load_row(int s, long r, const float* __restrict__ x,
                                         const __hip_bfloat16* __restrict__ hp16,
                                         const float* __restrict__ xadp, float* m) {
  if (s == 0 || s == 4) {
    const float4* p = (const float4*)((s == 0 ? x : xadp) + r * 32);
#pragma unroll
    for (int q = 0; q < 8; q++) {
      float4 v = p[q];
      m[q * 4 + 0] = v.x; m[q * 4 + 1] = v.y; m[q * 4 + 2] = v.z; m[q * 4 + 3] = v.w;
    }
  } else {
    const uint4* p = (const uint4*)(hp16 + ((long)(s - 1) * TN_ + r) * 32);
#pragma unroll
    for (int q = 0; q < 4; q++) {
      uint4 v = p[q];
      unsigned uu[4] = {v.x, v.y, v.z, v.w};
#pragma unroll
      for (int j = 0; j < 4; j++) {
        m[q * 8 + j * 2 + 0] = __uint_as_float(uu[j] << 16);
        m[q * 8 + j * 2 + 1] = __uint_as_float(uu[j] & 0xffff0000u);
      }
    }
  }
}

__global__ __launch_bounds__(256) void k_attn(const float* __restrict__ x,
                                              const __hip_bfloat16* __restrict__ hp16,
                                              const float* __restrict__ xadp,
                                              const float* __restrict__ prm,
                                              float* __restrict__ out) {
  __shared__ float Gs[1024], Hs[1024], g1s[32], g2s[32], hbs[32];
  __shared__ float g0sh;
  int tid = threadIdx.x;
  for (int i = tid; i < 1024; i += 256) { Gs[i] = prm[PRM_G + i]; Hs[i] = prm[PRM_H + i]; }
  if (tid < 32) { g1s[tid] = prm[PRM_G1 + tid]; g2s[tid] = prm[PRM_G2 + tid]; hbs[tid] = prm[PRM_HB + tid]; }
  if (tid == 0) g0sh = prm[PRM_G0];
  __syncthreads();
  long r = (long)blockIdx.x * 256 + tid;
  if (r >= TN_) return;
  float g0 = g0sh;
  float sc[5][5], d1[5], d2[5];
  float ms[32], mu[32], y[32];
#pragma unroll
  for (int s = 0; s < 5; s++) {
    load_row(s, r, x, hp16, xadp, ms);
    float a = 0.f, b = 0.f;
#pragma unroll
    for (int k = 0; k < 32; k++) { a = fmaf(ms[k], g1s[k], a); b = fmaf(ms[k], g2s[k], b); }
    d1[s] = a; d2[s] = b;
#pragma unroll
    for (int c = 0; c < 32; c++) {
      float s2 = 0.f;
#pragma unroll
      for (int k = 0; k < 32; k++) s2 = fmaf(ms[k], Gs[k * 32 + c], s2);
      y[c] = s2;
    }
#pragma unroll
    for (int u = 0; u < 5; u++) {
      load_row(u, r, x, hp16, xadp, mu);
      float dt = 0.f;
#pragma unroll
      for (int k = 0; k < 32; k++) dt = fmaf(y[k], mu[k], dt);
      sc[s][u] = dt;
    }
  }
  const float rs = 0.07216878364870322f;  // 1/sqrt(192)
  float abar[5];
#pragma unroll
  for (int u = 0; u < 5; u++) abar[u] = 0.f;
#pragma unroll
  for (int s = 0; s < 5; s++) {
    float e[5];
    float mx = -1e30f;
#pragma unroll
    for (int u = 0; u < 5; u++) {
      float v = (sc[s][u] + d1[s] + d2[u] + g0) * rs;
      e[u] = v;
      mx = fmaxf(mx, v);
    }
    float sm = 0.f;
#pragma unroll
    for (int u = 0; u < 5; u++) { e[u] = __expf(e[u] - mx); sm += e[u]; }
    float inv = 1.f / sm;
#pragma unroll
    for (int u = 0; u < 5; u++) abar[u] = fmaf(e[u], inv, abar[u]);
  }
  float z[32];
#pragma unroll
  for (int k = 0; k < 32; k++) z[k] = 0.f;
#pragma unroll
  for (int u = 0; u < 5; u++) {
    load_row(u, r, x, hp16, xadp, mu);
    float w = abar[u] * 0.2f;
#pragma unroll
    for (int k = 0; k < 32; k++) z[k] = fmaf(w, mu[k], z[k]);
  }
#pragma unroll
  for (int c = 0; c < 32; c++) {
    float o = hbs[c];
#pragma unroll
    for (int k = 0; k < 32; k++) o = fmaf(z[k], Hs[k * 32 + c], o);
    o = (o > 0.f) ? o : (__expf(o) - 1.f);
    out[r * 32 + c] = o;
  }
}

// ---------------- launch ----------------
extern "C" void kernel_launch(void* const* d_in, const int* in_sizes, int n_in,
                              void* d_out, int out_size, void* d_ws, size_t ws_size,
                              hipStream_t stream) {
  (void)in_sizes; (void)n_in; (void)out_size; (void)ws_size;
  const float* x          = (const float*)d_in[0];
  const float* timeoh     = (const float*)d_in[1];
  const int*   edges      = (const int*)d_in[2];
  const float* mlp_w      = (const float*)d_in[3];
  const float* mlp_b      = (const float*)d_in[4];
  const float* temb_w     = (const float*)d_in[5];
  const float* atten_pool = (const float*)d_in[6];
  const float* node2vec   = (const float*)d_in[7];
  const float* gcn_w      = (const float*)d_in[8];
  const float* gcn_b      = (const float*)d_in[9];
  const float* q_w  = (const float*)d_in[10];
  const float* q_b  = (const float*)d_in[11];
  const float* k_w  = (const float*)d_in[12];
  const float* k_b  = (const float*)d_in[13];
  const float* v_w  = (const float*)d_in[14];
  const float* v_b  = (const float*)d_in[15];
  const float* dense_w = (const float*)d_in[16];
  const float* dense_b = (const float*)d_in[17];
  float* out = (float*)d_out;
  char* ws = (char*)d_ws;

  float*    prm  = (float*)(ws + 0);
  float*    Mt   = (float*)(ws + 9216);
  int*      cnt  = (int*)(ws + 9472);
  int*      cur  = (int*)(ws + 129472);
  int*      offs = (int*)(ws + 249472);
  float*    ssrc = (float*)(ws + 369664);
  float*    sdst = (float*)(ws + 849664);
  float*    R    = (float*)(ws + 1329664);
  __hip_bfloat16* h16  = (__hip_bfloat16*)(ws + 1369664);
  int*      csr  = (int*)(ws + 9049664);
  __hip_bfloat16* hp16 = (__hip_bfloat16*)(ws + 12889664);
  float*    x1   = (float*)(ws + 35929664);
  float*    x2   = (float*)(ws + 51289664);
  short*    n2vA = (short*)(ws + 66649664);   //   640,000 B
  short*    xq0  = (short*)(ws + 67289664);   // 7,692,288 B
  short*    xq1  = (short*)(ws + 74983488);   // 7,692,288 B

  (void)hipMemsetAsync(cnt, 0, 120000, stream);

  k_prep<<<1, 256, 0, stream>>>(timeoh, temb_w, atten_pool, q_w, q_b, k_w, k_b,
                                v_w, v_b, dense_w, dense_b, prm);
  k_h<<<15000, 256, 0, stream>>>(x, mlp_w, mlp_b, prm, h16, ssrc, sdst);
  k_maxs<<<12, 256, 0, stream>>>(ssrc, sdst, Mt);
  k_hist<<<dim3(1250, 3), 256, 0, stream>>>(edges, cnt);
  k_scan<<<3, 1024, 0, stream>>>(cnt, offs, cur);
  k_fill<<<dim3(1250, 3), 256, 0, stream>>>(edges, cur, csr);
  k_gather<<<dim3(2500, 3), 256, 0, stream>>>(csr, offs, ssrc, sdst, Mt, h16, hp16);

  k_n2vA<<<157, 256, 0, stream>>>(node2vec, n2vA);
  k_pack0<<<1878, 256, 0, stream>>>(x, xq0);
  k_adj12<1><<<157, 512, 0, stream>>>(n2vA, xq0, x1, R, xq1);
  k_adj12<2><<<157, 512, 0, stream>>>(n2vA, xq1, x2, nullptr, nullptr);
  k_gcn<<<15000, 256, 0, stream>>>(x, x1, x2, R, gcn_w, gcn_b);
  k_attn<<<469, 256, 0, stream>>>(x, hp16, x2, prm, out);
}